// Round 1
// baseline (2668.207 us; speedup 1.0000x reference)
//
#include <hip/hip_runtime.h>

#define HDIM 256

// ---------------- small kernels ----------------

__global__ void init_deg_kernel(float* deg, int n) {
    int i = blockIdx.x * 256 + threadIdx.x;
    if (i < n) deg[i] = 1.0f;   // self-loop weight
}

__global__ void hist_deg_kernel(const int* __restrict__ dst, const float* __restrict__ w,
                                float* deg, int ne) {
    int e = blockIdx.x * 256 + threadIdx.x;
    if (e < ne) atomicAdd(&deg[dst[e]], w[e]);
}

__global__ void rsqrt_kernel(float* deg, int n) {
    int i = blockIdx.x * 256 + threadIdx.x;
    if (i < n) { float d = deg[i]; deg[i] = d > 0.f ? rsqrtf(d) : 0.f; }
}

__global__ void hist_cnt_kernel(const int* __restrict__ dst, int* cnt, int ne) {
    int e = blockIdx.x * 256 + threadIdx.x;
    if (e < ne) atomicAdd(&cnt[dst[e]], 1);
}

// single-block exclusive scan over cnt[n] -> rptr[0..n], cur[i]=rptr[i]
__global__ __launch_bounds__(1024) void scan_kernel(const int* __restrict__ cnt,
                                                    int* __restrict__ rptr,
                                                    int* __restrict__ cur, int n) {
    const int per = (n + 1023) / 1024;
    const int tid = threadIdx.x;
    const int start = tid * per;
    const int end = min(start + per, n);
    int local = 0;
    for (int i = start; i < end; ++i) local += cnt[i];
    const int lane = tid & 63, wid = tid >> 6;
    int incl = local;
    for (int d = 1; d < 64; d <<= 1) { int m = __shfl_up(incl, d); if (lane >= d) incl += m; }
    __shared__ int wsum[16];
    if (lane == 63) wsum[wid] = incl;
    __syncthreads();
    if (tid < 16) {
        int v = wsum[tid];
        int iv = v;
        for (int d = 1; d < 16; d <<= 1) { int m = __shfl_up(iv, d, 16); if (tid >= d) iv += m; }
        wsum[tid] = iv - v;   // exclusive offset per wave
    }
    __syncthreads();
    int run = (incl - local) + wsum[wid];   // exclusive prefix for this thread's segment
    for (int i = start; i < end; ++i) { int c = cnt[i]; rptr[i] = run; cur[i] = run; run += c; }
    if (start < n && end == n) rptr[n] = run;
}

// bucket edges by dst; store src and precomputed norm per sorted slot
__global__ void fill_kernel(const int* __restrict__ src, const int* __restrict__ dst,
                            const float* __restrict__ w, const float* __restrict__ dinv,
                            int* cur, int* __restrict__ ssrc, float* __restrict__ snrm, int ne) {
    int e = blockIdx.x * 256 + threadIdx.x;
    if (e < ne) {
        int s = src[e], d = dst[e];
        int pos = atomicAdd(&cur[d], 1);
        ssrc[pos] = s;
        snrm[pos] = dinv[s] * w[e] * dinv[d];
    }
}

// one block (256 thr) per dst node: acc = dinv^2 * X[v] + sum norm * X[src]
__global__ __launch_bounds__(256) void agg_kernel(const float* __restrict__ X,
                                                  const int* __restrict__ rptr,
                                                  const int* __restrict__ ssrc,
                                                  const float* __restrict__ snrm,
                                                  const float* __restrict__ dinv,
                                                  float* __restrict__ out) {
    const int v = blockIdx.x;
    const int t = threadIdx.x;
    const float dv = dinv[v];
    const size_t vo = (size_t)v * HDIM + t;
    float acc = dv * dv * X[vo];
    const int b = rptr[v], e = rptr[v + 1];
    for (int i = b; i < e; ++i) {
        int s = ssrc[i];
        float nr = snrm[i];
        acc += nr * X[(size_t)s * HDIM + t];
    }
    out[vo] = acc;
}

// ---------------- fused NT GEMM (C = A @ W^T) with LN epilogues ----------------
// MODE 0: out[M][256] = relu(LN(C + bias + res; g1,b1))                      (stage A)
// MODE 1: y = relu(LN(C + bias + res; g1,b1)); out = LN(y + orig; g2,b2)     (stage B + final)
// MODE 2: y = relu(LN(C + bias; g1,b1)); out[M] = dot(y, W2) + b2s[0]        (edge MLP)
// Tile: BM=64 rows, BN=256 (full), BK=32. 256 thr: ty=tid>>4 owns rows ty*4..+3,
// tx=tid&15 owns cols {q*64 + tx*4 + r : q<4, r<4}  (conflict-free ds_read_b128).
template <int MODE>
__global__ __launch_bounds__(256) void gemm_ln_kernel(
    const float* __restrict__ A, int lda, int K, int M,
    const float* __restrict__ W,      // [256][K] row-major
    const float* __restrict__ bias,   // [256]
    const float* __restrict__ res,    // [M][256] or null
    const float* __restrict__ orig,   // [M][256] or null
    const float* __restrict__ g1v, const float* __restrict__ b1v,
    const float* __restrict__ g2v, const float* __restrict__ b2v,
    const float* __restrict__ W2, const float* __restrict__ b2s,
    float* __restrict__ out) {
    __shared__ float As[32][68];    // [k][m], padded to keep 16B alignment + spread banks
    __shared__ float Bs[32][HDIM];  // [k][n]
    const int tid = threadIdx.x;
    const int ty = tid >> 4, tx = tid & 15;
    const int m0 = blockIdx.x * 64;

    float acc[4][16];
#pragma unroll
    for (int i = 0; i < 4; ++i)
#pragma unroll
        for (int j = 0; j < 16; ++j) acc[i][j] = 0.f;

    const int kT = (K + 31) >> 5;
    for (int kt = 0; kt < kT; ++kt) {
        const int k0 = kt << 5;
        // stage A tile (transposed into LDS), zero-pad OOB rows/ragged K
        {
            const int am = tid >> 3;         // 0..31
            const int kb = (tid & 7) << 2;   // 0,4,...,28
#pragma unroll
            for (int half = 0; half < 2; ++half) {
                const int m = am + (half << 5);
                const int gm = m0 + m;
#pragma unroll
                for (int j = 0; j < 4; ++j) {
                    const int kg = k0 + kb + j;
                    float v = 0.f;
                    if (gm < M && kg < K) v = A[(size_t)gm * lda + kg];
                    As[kb + j][m] = v;
                }
            }
        }
        // stage B tile
        {
#pragma unroll 8
            for (int kk = 0; kk < 32; ++kk) {
                const int kg = k0 + kk;
                Bs[kk][tid] = (kg < K) ? W[tid * K + kg] : 0.f;
            }
        }
        __syncthreads();
#pragma unroll
        for (int kk = 0; kk < 32; ++kk) {
            const float4 a4 = *(const float4*)(&As[kk][ty << 2]);
            float av[4] = {a4.x, a4.y, a4.z, a4.w};
            float bv[16];
#pragma unroll
            for (int q = 0; q < 4; ++q) {
                const float4 b4 = *(const float4*)(&Bs[kk][q * 64 + (tx << 2)]);
                bv[q * 4 + 0] = b4.x; bv[q * 4 + 1] = b4.y;
                bv[q * 4 + 2] = b4.z; bv[q * 4 + 3] = b4.w;
            }
#pragma unroll
            for (int i = 0; i < 4; ++i)
#pragma unroll
                for (int j = 0; j < 16; ++j)
                    acc[i][j] = fmaf(av[i], bv[j], acc[i][j]);
        }
        __syncthreads();
    }

    // ---------------- epilogue ----------------
    const int cb = tx << 2;   // col = q*64 + cb + r
    float biasv[16], g1_[16], b1_[16];
#pragma unroll
    for (int q = 0; q < 4; ++q) {
        *(float4*)&biasv[q * 4] = *(const float4*)(bias + q * 64 + cb);
        *(float4*)&g1_[q * 4]   = *(const float4*)(g1v + q * 64 + cb);
        *(float4*)&b1_[q * 4]   = *(const float4*)(b1v + q * 64 + cb);
    }
    float g2_[16], b2_[16], w2_[16];
    if constexpr (MODE == 1) {
#pragma unroll
        for (int q = 0; q < 4; ++q) {
            *(float4*)&g2_[q * 4] = *(const float4*)(g2v + q * 64 + cb);
            *(float4*)&b2_[q * 4] = *(const float4*)(b2v + q * 64 + cb);
        }
    }
    float b2sc = 0.f;
    if constexpr (MODE == 2) {
#pragma unroll
        for (int q = 0; q < 4; ++q) *(float4*)&w2_[q * 4] = *(const float4*)(W2 + q * 64 + cb);
        b2sc = b2s[0];
    }

#pragma unroll
    for (int i = 0; i < 4; ++i) {
        const int gr = m0 + (ty << 2) + i;
        if (gr < M) {
            float v[16];
            if constexpr (MODE == 2) {
#pragma unroll
                for (int j = 0; j < 16; ++j) v[j] = acc[i][j] + biasv[j];
            } else {
#pragma unroll
                for (int q = 0; q < 4; ++q) {
                    const float4 r4 = *(const float4*)(res + (size_t)gr * HDIM + q * 64 + cb);
                    v[q * 4 + 0] = acc[i][q * 4 + 0] + biasv[q * 4 + 0] + r4.x;
                    v[q * 4 + 1] = acc[i][q * 4 + 1] + biasv[q * 4 + 1] + r4.y;
                    v[q * 4 + 2] = acc[i][q * 4 + 2] + biasv[q * 4 + 2] + r4.z;
                    v[q * 4 + 3] = acc[i][q * 4 + 3] + biasv[q * 4 + 3] + r4.w;
                }
            }
            float s1 = 0.f, s2 = 0.f;
#pragma unroll
            for (int j = 0; j < 16; ++j) { s1 += v[j]; s2 += v[j] * v[j]; }
#pragma unroll
            for (int d = 1; d < 16; d <<= 1) { s1 += __shfl_xor(s1, d); s2 += __shfl_xor(s2, d); }
            const float mu = s1 * (1.f / HDIM);
            const float var = s2 * (1.f / HDIM) - mu * mu;
            const float rs = rsqrtf(var + 1e-5f);

            if constexpr (MODE == 2) {
                float part = 0.f;
#pragma unroll
                for (int j = 0; j < 16; ++j) {
                    float y = fmaxf((v[j] - mu) * rs * g1_[j] + b1_[j], 0.f);
                    part = fmaf(y, w2_[j], part);
                }
#pragma unroll
                for (int d = 1; d < 16; d <<= 1) part += __shfl_xor(part, d);
                if (tx == 0) out[gr] = part + b2sc;
            } else if constexpr (MODE == 0) {
#pragma unroll
                for (int q = 0; q < 4; ++q) {
                    float4 o4;
                    float* o = (float*)&o4;
#pragma unroll
                    for (int r = 0; r < 4; ++r) {
                        int j = q * 4 + r;
                        o[r] = fmaxf((v[j] - mu) * rs * g1_[j] + b1_[j], 0.f);
                    }
                    *(float4*)(out + (size_t)gr * HDIM + q * 64 + cb) = o4;
                }
            } else {  // MODE 1: second residual + second LN
                float u[16];
#pragma unroll
                for (int q = 0; q < 4; ++q) {
                    const float4 r4 = *(const float4*)(orig + (size_t)gr * HDIM + q * 64 + cb);
                    const float* rr = (const float*)&r4;
#pragma unroll
                    for (int r = 0; r < 4; ++r) {
                        int j = q * 4 + r;
                        float y = fmaxf((v[j] - mu) * rs * g1_[j] + b1_[j], 0.f);
                        u[j] = y + rr[r];
                    }
                }
                float t1 = 0.f, t2 = 0.f;
#pragma unroll
                for (int j = 0; j < 16; ++j) { t1 += u[j]; t2 += u[j] * u[j]; }
#pragma unroll
                for (int d = 1; d < 16; d <<= 1) { t1 += __shfl_xor(t1, d); t2 += __shfl_xor(t2, d); }
                const float mu2 = t1 * (1.f / HDIM);
                const float var2 = t2 * (1.f / HDIM) - mu2 * mu2;
                const float rs2 = rsqrtf(var2 + 1e-5f);
#pragma unroll
                for (int q = 0; q < 4; ++q) {
                    float4 o4;
                    float* o = (float*)&o4;
#pragma unroll
                    for (int r = 0; r < 4; ++r) {
                        int j = q * 4 + r;
                        o[r] = (u[j] - mu2) * rs2 * g2_[j] + b2_[j];
                    }
                    *(float4*)(out + (size_t)gr * HDIM + q * 64 + cb) = o4;
                }
            }
        }
    }
}

// ---------------- launch ----------------

extern "C" void kernel_launch(void* const* d_in, const int* in_sizes, int n_in,
                              void* d_out, int out_size, void* d_ws, size_t ws_size,
                              hipStream_t stream) {
    const float* x    = (const float*)d_in[0];
    const int*   eib  = (const int*)d_in[1];
    const float* eab  = (const float*)d_in[2];
    const int*   eit  = (const int*)d_in[3];
    const float* eat  = (const float*)d_in[4];
    const float* Wb   = (const float*)d_in[5];
    const float* bb   = (const float*)d_in[6];
    const float* Wt   = (const float*)d_in[7];
    const float* bt   = (const float*)d_in[8];
    const float* W1   = (const float*)d_in[9];
    const float* b1   = (const float*)d_in[10];
    const float* g1   = (const float*)d_in[11];
    const float* be1  = (const float*)d_in[12];
    const float* W2   = (const float*)d_in[13];
    const float* b2   = (const float*)d_in[14];
    const float* gs   = (const float*)d_in[15];
    const float* bs   = (const float*)d_in[16];
    const float* gt   = (const float*)d_in[17];
    const float* btn  = (const float*)d_in[18];

    const int Nn = in_sizes[0] / HDIM;     // 50000
    const int Ne = in_sizes[2];            // 800000
    const int Ka = in_sizes[4] / Ne;       // 107

    const int* src_b = eib;  const int* dst_b = eib + Ne;
    const int* src_t = eit;  const int* dst_t = eit + Ne;

    char* w = (char*)d_ws;
    float* x1   = (float*)w; w += (size_t)Nn * HDIM * 4;
    float* aggb = (float*)w; w += (size_t)Nn * HDIM * 4;
    float* wtmp = (float*)w; w += (size_t)Ne * 4;
    float* dinv = (float*)w; w += (size_t)Nn * 4;
    int*   cnt  = (int*)w;   w += (size_t)Nn * 4;
    int*   rptr = (int*)w;   w += (size_t)(Nn + 2) * 4;
    int*   cur  = (int*)w;   w += (size_t)Nn * 4;
    int*   ssrc = (int*)w;   w += (size_t)Ne * 4;
    float* snrm = (float*)w; w += (size_t)Ne * 4;

    float* out = (float*)d_out;
    dim3 b256(256);
    dim3 gN((Nn + 255) / 256), gE((Ne + 255) / 256);
    dim3 gGemmN((Nn + 63) / 64), gGemmE((Ne + 63) / 64);

    // ---- stage A: BOLD GCN (aggregate-first, then transform+LN fused) ----
    init_deg_kernel<<<gN, b256, 0, stream>>>(dinv, Nn);
    hist_deg_kernel<<<gE, b256, 0, stream>>>(dst_b, eab, dinv, Ne);
    rsqrt_kernel<<<gN, b256, 0, stream>>>(dinv, Nn);
    hipMemsetAsync(cnt, 0, (size_t)Nn * 4, stream);
    hist_cnt_kernel<<<gE, b256, 0, stream>>>(dst_b, cnt, Ne);
    scan_kernel<<<dim3(1), dim3(1024), 0, stream>>>(cnt, rptr, cur, Nn);
    fill_kernel<<<gE, b256, 0, stream>>>(src_b, dst_b, eab, dinv, cur, ssrc, snrm, Ne);
    agg_kernel<<<dim3(Nn), b256, 0, stream>>>(x, rptr, ssrc, snrm, dinv, aggb);
    gemm_ln_kernel<0><<<gGemmN, b256, 0, stream>>>(
        aggb, HDIM, HDIM, Nn, Wb, bb, x, nullptr, gs, bs,
        nullptr, nullptr, nullptr, nullptr, x1);

    // ---- temporal edge-weight MLP (fused GEMM + LN + dot) ----
    gemm_ln_kernel<2><<<gGemmE, b256, 0, stream>>>(
        eat, Ka, Ka, Ne, W1, b1, nullptr, nullptr, g1, be1,
        nullptr, nullptr, W2, b2, wtmp);

    // ---- stage B: temporal GCN + final LN (all fused in epilogue) ----
    init_deg_kernel<<<gN, b256, 0, stream>>>(dinv, Nn);
    hist_deg_kernel<<<gE, b256, 0, stream>>>(dst_t, wtmp, dinv, Ne);
    rsqrt_kernel<<<gN, b256, 0, stream>>>(dinv, Nn);
    hipMemsetAsync(cnt, 0, (size_t)Nn * 4, stream);
    hist_cnt_kernel<<<gE, b256, 0, stream>>>(dst_t, cnt, Ne);
    scan_kernel<<<dim3(1), dim3(1024), 0, stream>>>(cnt, rptr, cur, Nn);
    fill_kernel<<<gE, b256, 0, stream>>>(src_t, dst_t, wtmp, dinv, cur, ssrc, snrm, Ne);
    agg_kernel<<<dim3(Nn), b256, 0, stream>>>(x1, rptr, ssrc, snrm, dinv, aggb);
    gemm_ln_kernel<1><<<gGemmN, b256, 0, stream>>>(
        aggb, HDIM, HDIM, Nn, Wt, bt, x1, x, gt, btn,
        gs, bs, nullptr, nullptr, out);
}

// Round 2
// 1544.338 us; speedup vs baseline: 1.7277x; 1.7277x over previous
//
#include <hip/hip_runtime.h>

#define HDIM 256
#define KA 107
#define KAP 128

typedef short bf16x8 __attribute__((ext_vector_type(8)));
typedef float f32x4 __attribute__((ext_vector_type(4)));

__device__ inline unsigned short f2bf(float f) {
    union { float f; unsigned u; } v; v.f = f;
    unsigned r = v.u + 0x7fff + ((v.u >> 16) & 1);
    return (unsigned short)(r >> 16);
}

// ---------------- small kernels ----------------

__global__ void init_deg_kernel(float* deg, int n) {
    int i = blockIdx.x * 256 + threadIdx.x;
    if (i < n) deg[i] = 1.0f;   // self-loop weight
}

__global__ void hist_deg_kernel(const int* __restrict__ dst, const float* __restrict__ w,
                                float* deg, int ne) {
    int e = blockIdx.x * 256 + threadIdx.x;
    if (e < ne) atomicAdd(&deg[dst[e]], w[e]);
}

__global__ void rsqrt_kernel(float* deg, int n) {
    int i = blockIdx.x * 256 + threadIdx.x;
    if (i < n) { float d = deg[i]; deg[i] = d > 0.f ? rsqrtf(d) : 0.f; }
}

__global__ void hist_cnt_kernel(const int* __restrict__ dst, int* cnt, int ne) {
    int e = blockIdx.x * 256 + threadIdx.x;
    if (e < ne) atomicAdd(&cnt[dst[e]], 1);
}

// single-block exclusive scan over cnt[n] -> rptr[0..n], cur[i]=rptr[i]
__global__ __launch_bounds__(1024) void scan_kernel(const int* __restrict__ cnt,
                                                    int* __restrict__ rptr,
                                                    int* __restrict__ cur, int n) {
    const int per = (n + 1023) / 1024;
    const int tid = threadIdx.x;
    const int start = tid * per;
    const int end = min(start + per, n);
    int local = 0;
    for (int i = start; i < end; ++i) local += cnt[i];
    const int lane = tid & 63, wid = tid >> 6;
    int incl = local;
    for (int d = 1; d < 64; d <<= 1) { int m = __shfl_up(incl, d); if (lane >= d) incl += m; }
    __shared__ int wsum[16];
    if (lane == 63) wsum[wid] = incl;
    __syncthreads();
    if (tid < 16) {
        int v = wsum[tid];
        int iv = v;
        for (int d = 1; d < 16; d <<= 1) { int m = __shfl_up(iv, d, 16); if (tid >= d) iv += m; }
        wsum[tid] = iv - v;   // exclusive offset per wave
    }
    __syncthreads();
    int run = (incl - local) + wsum[wid];
    for (int i = start; i < end; ++i) { int c = cnt[i]; rptr[i] = run; cur[i] = run; run += c; }
    if (start < n && end == n) rptr[n] = run;
}

__global__ void fill_kernel(const int* __restrict__ src, const int* __restrict__ dst,
                            const float* __restrict__ w, const float* __restrict__ dinv,
                            int* cur, int* __restrict__ ssrc, float* __restrict__ snrm, int ne) {
    int e = blockIdx.x * 256 + threadIdx.x;
    if (e < ne) {
        int s = src[e], d = dst[e];
        int pos = atomicAdd(&cur[d], 1);
        ssrc[pos] = s;
        snrm[pos] = dinv[s] * w[e] * dinv[d];
    }
}

// one block (256 thr) per dst node
__global__ __launch_bounds__(256) void agg_kernel(const float* __restrict__ X,
                                                  const int* __restrict__ rptr,
                                                  const int* __restrict__ ssrc,
                                                  const float* __restrict__ snrm,
                                                  const float* __restrict__ dinv,
                                                  float* __restrict__ out) {
    const int v = blockIdx.x;
    const int t = threadIdx.x;
    const float dv = dinv[v];
    const size_t vo = (size_t)v * HDIM + t;
    float acc = dv * dv * X[vo];
    const int b = rptr[v], e = rptr[v + 1];
    for (int i = b; i < e; ++i) {
        int s = ssrc[i];
        float nr = snrm[i];
        acc += nr * X[(size_t)s * HDIM + t];
    }
    out[vo] = acc;
}

// ---------------- bf16 weight prep ----------------
__global__ void prep_w_kernel(const float* __restrict__ W1, unsigned short* __restrict__ Wp) {
    int i = blockIdx.x * 256 + threadIdx.x;   // over 256*KAP
    if (i < 256 * KAP) {
        int n = i >> 7, k = i & (KAP - 1);
        Wp[i] = (k < KA) ? f2bf(W1[n * KA + k]) : (unsigned short)0;
    }
}

// ---------------- edge MLP: bf16 MFMA GEMM + fused LN + dot(W2) ----------------
// out[m] = dot(relu(LN(A[m]@W1^T + b1; g1, be1)), W2) + b2
// Block: 64 rows, 256 cols, 4 waves (wave wv owns cols wv*64..+63).
__global__ __launch_bounds__(256) void mlp_mfma_kernel(
    const float* __restrict__ A,            // [M][107] f32
    const unsigned short* __restrict__ Wp,  // [256][128] bf16
    const float* __restrict__ b1v, const float* __restrict__ g1v,
    const float* __restrict__ be1v, const float* __restrict__ W2,
    const float* __restrict__ b2s, float* __restrict__ out, int M) {
    __shared__ unsigned short As[64][136];   // padded stride: 272B/row -> banks rotate
    __shared__ float ps1[64][4];
    __shared__ float ps2[64][4];
    __shared__ float pd[64][4];

    const int tid = threadIdx.x;
    const int m0 = blockIdx.x * 64;
    const int l = tid & 63, wv = tid >> 6;
    const int g = l >> 4, c = l & 15;

    // zero-pad k in [107,128)
    for (int z = tid; z < 64 * 32; z += 256) {
        int r = z >> 5, k = 96 + (z & 31);
        if (k >= KA) As[r][k] = 0;
    }
    // stage A tile: 64*107 = 6848 f32 = 1712 float4 (flat, perfectly coalesced)
    {
        const float* base = A + (size_t)m0 * KA;
        for (int it = 0; it < 7; ++it) {
            int idx = it * 256 + tid;
            if (idx < 1712) {
                float4 v4 = *(const float4*)(base + (size_t)idx * 4);
                const float* vv = (const float*)&v4;
                int e0 = idx * 4;
#pragma unroll
                for (int e = 0; e < 4; ++e) {
                    int ge = e0 + e;
                    int r = ge / KA;         // const divide -> magic mul
                    int k = ge - r * KA;
                    As[r][k] = f2bf(vv[e]);
                }
            }
        }
    }
    __syncthreads();

    f32x4 acc[4][4];
#pragma unroll
    for (int rt = 0; rt < 4; ++rt)
#pragma unroll
        for (int ct = 0; ct < 4; ++ct) acc[rt][ct] = (f32x4){0.f, 0.f, 0.f, 0.f};

    // B fragment base: col = wv*64 + ct*16 + c, k = ks*32 + g*8
    const unsigned short* wbase = Wp + ((size_t)(wv * 64 + c)) * KAP + g * 8;
#pragma unroll
    for (int ks = 0; ks < 4; ++ks) {
        bf16x8 af[4];
#pragma unroll
        for (int rt = 0; rt < 4; ++rt)
            af[rt] = *(const bf16x8*)&As[rt * 16 + c][ks * 32 + g * 8];
#pragma unroll
        for (int ct = 0; ct < 4; ++ct) {
            bf16x8 bfr = *(const bf16x8*)(wbase + ct * 16 * KAP + ks * 32);
#pragma unroll
            for (int rt = 0; rt < 4; ++rt)
                acc[rt][ct] = __builtin_amdgcn_mfma_f32_16x16x32_bf16(af[rt], bfr, acc[rt][ct], 0, 0, 0);
        }
    }

    // ---- epilogue: per-row LN over 256 cols (cross-wave), relu, dot W2 ----
    float b1c[4], g1c[4], bec[4], w2c[4];
#pragma unroll
    for (int ct = 0; ct < 4; ++ct) {
        int col = wv * 64 + ct * 16 + c;
        b1c[ct] = b1v[col]; g1c[ct] = g1v[col]; bec[ct] = be1v[col]; w2c[ct] = W2[col];
    }

    float rs1[4][4], rs2[4][4];
#pragma unroll
    for (int rt = 0; rt < 4; ++rt)
#pragma unroll
        for (int reg = 0; reg < 4; ++reg) {
            float t1 = 0.f, t2 = 0.f;
#pragma unroll
            for (int ct = 0; ct < 4; ++ct) {
                float v = acc[rt][ct][reg] + b1c[ct];
                t1 += v; t2 += v * v;
            }
#pragma unroll
            for (int d = 1; d < 16; d <<= 1) { t1 += __shfl_xor(t1, d); t2 += __shfl_xor(t2, d); }
            rs1[rt][reg] = t1; rs2[rt][reg] = t2;
        }
    if (c == 0) {
#pragma unroll
        for (int rt = 0; rt < 4; ++rt)
#pragma unroll
            for (int reg = 0; reg < 4; ++reg) {
                ps1[rt * 16 + g * 4 + reg][wv] = rs1[rt][reg];
                ps2[rt * 16 + g * 4 + reg][wv] = rs2[rt][reg];
            }
    }
    __syncthreads();

    float dsum[4][4];
#pragma unroll
    for (int rt = 0; rt < 4; ++rt)
#pragma unroll
        for (int reg = 0; reg < 4; ++reg) {
            const int row = rt * 16 + g * 4 + reg;
            float4 p1 = *(const float4*)ps1[row];
            float4 p2 = *(const float4*)ps2[row];
            float s1 = p1.x + p1.y + p1.z + p1.w;
            float s2 = p2.x + p2.y + p2.z + p2.w;
            float mu = s1 * (1.f / HDIM);
            float var = s2 * (1.f / HDIM) - mu * mu;
            float rstd = rsqrtf(var + 1e-5f);
            float dacc = 0.f;
#pragma unroll
            for (int ct = 0; ct < 4; ++ct) {
                float v = acc[rt][ct][reg] + b1c[ct];
                float y = fmaxf((v - mu) * rstd * g1c[ct] + bec[ct], 0.f);
                dacc = fmaf(y, w2c[ct], dacc);
            }
#pragma unroll
            for (int d = 1; d < 16; d <<= 1) dacc += __shfl_xor(dacc, d);
            dsum[rt][reg] = dacc;
        }
    if (c == 0) {
#pragma unroll
        for (int rt = 0; rt < 4; ++rt)
#pragma unroll
            for (int reg = 0; reg < 4; ++reg)
                pd[rt * 16 + g * 4 + reg][wv] = dsum[rt][reg];
    }
    __syncthreads();

    if (tid < 64) {
        float4 p = *(const float4*)pd[tid];
        int gr = m0 + tid;
        if (gr < M) out[gr] = p.x + p.y + p.z + p.w + b2s[0];
    }
}

// ---------------- fused NT GEMM (C = A @ W^T) with LN epilogues (f32) ----------------
// MODE 0: out[M][256] = relu(LN(C + bias + res; g1,b1))
// MODE 1: y = relu(LN(C + bias + res; g1,b1)); out = LN(y + orig; g2,b2)
template <int MODE>
__global__ __launch_bounds__(256) void gemm_ln_kernel(
    const float* __restrict__ A, int lda, int K, int M,
    const float* __restrict__ W,
    const float* __restrict__ bias,
    const float* __restrict__ res,
    const float* __restrict__ orig,
    const float* __restrict__ g1v, const float* __restrict__ b1v,
    const float* __restrict__ g2v, const float* __restrict__ b2v,
    float* __restrict__ out) {
    __shared__ float As[32][68];
    __shared__ float Bs[32][HDIM];
    const int tid = threadIdx.x;
    const int ty = tid >> 4, tx = tid & 15;
    const int m0 = blockIdx.x * 64;

    float acc[4][16];
#pragma unroll
    for (int i = 0; i < 4; ++i)
#pragma unroll
        for (int j = 0; j < 16; ++j) acc[i][j] = 0.f;

    const int kT = (K + 31) >> 5;
    for (int kt = 0; kt < kT; ++kt) {
        const int k0 = kt << 5;
        {
            const int am = tid >> 3;
            const int kb = (tid & 7) << 2;
#pragma unroll
            for (int half = 0; half < 2; ++half) {
                const int m = am + (half << 5);
                const int gm = m0 + m;
#pragma unroll
                for (int j = 0; j < 4; ++j) {
                    const int kg = k0 + kb + j;
                    float v = 0.f;
                    if (gm < M && kg < K) v = A[(size_t)gm * lda + kg];
                    As[kb + j][m] = v;
                }
            }
        }
        {
#pragma unroll 8
            for (int kk = 0; kk < 32; ++kk) {
                const int kg = k0 + kk;
                Bs[kk][tid] = (kg < K) ? W[tid * K + kg] : 0.f;
            }
        }
        __syncthreads();
#pragma unroll
        for (int kk = 0; kk < 32; ++kk) {
            const float4 a4 = *(const float4*)(&As[kk][ty << 2]);
            float av[4] = {a4.x, a4.y, a4.z, a4.w};
            float bv[16];
#pragma unroll
            for (int q = 0; q < 4; ++q) {
                const float4 b4 = *(const float4*)(&Bs[kk][q * 64 + (tx << 2)]);
                bv[q * 4 + 0] = b4.x; bv[q * 4 + 1] = b4.y;
                bv[q * 4 + 2] = b4.z; bv[q * 4 + 3] = b4.w;
            }
#pragma unroll
            for (int i = 0; i < 4; ++i)
#pragma unroll
                for (int j = 0; j < 16; ++j)
                    acc[i][j] = fmaf(av[i], bv[j], acc[i][j]);
        }
        __syncthreads();
    }

    const int cb = tx << 2;
    float biasv[16], g1_[16], b1_[16];
#pragma unroll
    for (int q = 0; q < 4; ++q) {
        *(float4*)&biasv[q * 4] = *(const float4*)(bias + q * 64 + cb);
        *(float4*)&g1_[q * 4]   = *(const float4*)(g1v + q * 64 + cb);
        *(float4*)&b1_[q * 4]   = *(const float4*)(b1v + q * 64 + cb);
    }
    float g2_[16], b2_[16];
    if constexpr (MODE == 1) {
#pragma unroll
        for (int q = 0; q < 4; ++q) {
            *(float4*)&g2_[q * 4] = *(const float4*)(g2v + q * 64 + cb);
            *(float4*)&b2_[q * 4] = *(const float4*)(b2v + q * 64 + cb);
        }
    }

#pragma unroll
    for (int i = 0; i < 4; ++i) {
        const int gr = m0 + (ty << 2) + i;
        if (gr < M) {
            float v[16];
#pragma unroll
            for (int q = 0; q < 4; ++q) {
                const float4 r4 = *(const float4*)(res + (size_t)gr * HDIM + q * 64 + cb);
                v[q * 4 + 0] = acc[i][q * 4 + 0] + biasv[q * 4 + 0] + r4.x;
                v[q * 4 + 1] = acc[i][q * 4 + 1] + biasv[q * 4 + 1] + r4.y;
                v[q * 4 + 2] = acc[i][q * 4 + 2] + biasv[q * 4 + 2] + r4.z;
                v[q * 4 + 3] = acc[i][q * 4 + 3] + biasv[q * 4 + 3] + r4.w;
            }
            float s1 = 0.f, s2 = 0.f;
#pragma unroll
            for (int j = 0; j < 16; ++j) { s1 += v[j]; s2 += v[j] * v[j]; }
#pragma unroll
            for (int d = 1; d < 16; d <<= 1) { s1 += __shfl_xor(s1, d); s2 += __shfl_xor(s2, d); }
            const float mu = s1 * (1.f / HDIM);
            const float var = s2 * (1.f / HDIM) - mu * mu;
            const float rs = rsqrtf(var + 1e-5f);

            if constexpr (MODE == 0) {
#pragma unroll
                for (int q = 0; q < 4; ++q) {
                    float4 o4;
                    float* o = (float*)&o4;
#pragma unroll
                    for (int r = 0; r < 4; ++r) {
                        int j = q * 4 + r;
                        o[r] = fmaxf((v[j] - mu) * rs * g1_[j] + b1_[j], 0.f);
                    }
                    *(float4*)(out + (size_t)gr * HDIM + q * 64 + cb) = o4;
                }
            } else {
                float u[16];
#pragma unroll
                for (int q = 0; q < 4; ++q) {
                    const float4 r4 = *(const float4*)(orig + (size_t)gr * HDIM + q * 64 + cb);
                    const float* rr = (const float*)&r4;
#pragma unroll
                    for (int r = 0; r < 4; ++r) {
                        int j = q * 4 + r;
                        float y = fmaxf((v[j] - mu) * rs * g1_[j] + b1_[j], 0.f);
                        u[j] = y + rr[r];
                    }
                }
                float t1 = 0.f, t2 = 0.f;
#pragma unroll
                for (int j = 0; j < 16; ++j) { t1 += u[j]; t2 += u[j] * u[j]; }
#pragma unroll
                for (int d = 1; d < 16; d <<= 1) { t1 += __shfl_xor(t1, d); t2 += __shfl_xor(t2, d); }
                const float mu2 = t1 * (1.f / HDIM);
                const float var2 = t2 * (1.f / HDIM) - mu2 * mu2;
                const float rs2 = rsqrtf(var2 + 1e-5f);
#pragma unroll
                for (int q = 0; q < 4; ++q) {
                    float4 o4;
                    float* o = (float*)&o4;
#pragma unroll
                    for (int r = 0; r < 4; ++r) {
                        int j = q * 4 + r;
                        o[r] = (u[j] - mu2) * rs2 * g2_[j] + b2_[j];
                    }
                    *(float4*)(out + (size_t)gr * HDIM + q * 64 + cb) = o4;
                }
            }
        }
    }
}

// ---------------- launch ----------------

extern "C" void kernel_launch(void* const* d_in, const int* in_sizes, int n_in,
                              void* d_out, int out_size, void* d_ws, size_t ws_size,
                              hipStream_t stream) {
    const float* x    = (const float*)d_in[0];
    const int*   eib  = (const int*)d_in[1];
    const float* eab  = (const float*)d_in[2];
    const int*   eit  = (const int*)d_in[3];
    const float* eat  = (const float*)d_in[4];
    const float* Wb   = (const float*)d_in[5];
    const float* bb   = (const float*)d_in[6];
    const float* Wt   = (const float*)d_in[7];
    const float* bt   = (const float*)d_in[8];
    const float* W1   = (const float*)d_in[9];
    const float* b1   = (const float*)d_in[10];
    const float* g1   = (const float*)d_in[11];
    const float* be1  = (const float*)d_in[12];
    const float* W2   = (const float*)d_in[13];
    const float* b2   = (const float*)d_in[14];
    const float* gs   = (const float*)d_in[15];
    const float* bs   = (const float*)d_in[16];
    const float* gt   = (const float*)d_in[17];
    const float* btn  = (const float*)d_in[18];

    const int Nn = in_sizes[0] / HDIM;     // 50000
    const int Ne = in_sizes[2];            // 800000

    const int* src_b = eib;  const int* dst_b = eib + Ne;
    const int* src_t = eit;  const int* dst_t = eit + Ne;

    char* w = (char*)d_ws;
    float* x1   = (float*)w; w += (size_t)Nn * HDIM * 4;
    float* aggb = (float*)w; w += (size_t)Nn * HDIM * 4;
    float* wtmp = (float*)w; w += (size_t)Ne * 4;
    float* dinv = (float*)w; w += (size_t)Nn * 4;
    int*   cnt  = (int*)w;   w += (size_t)Nn * 4;
    int*   rptr = (int*)w;   w += (size_t)(Nn + 2) * 4;
    int*   cur  = (int*)w;   w += (size_t)Nn * 4;
    int*   ssrc = (int*)w;   w += (size_t)Ne * 4;
    float* snrm = (float*)w; w += (size_t)Ne * 4;
    unsigned short* W1p = (unsigned short*)w; w += (size_t)256 * KAP * 2;

    float* out = (float*)d_out;
    dim3 b256(256);
    dim3 gN((Nn + 255) / 256), gE((Ne + 255) / 256);
    dim3 gGemmN((Nn + 63) / 64), gGemmE((Ne + 63) / 64);

    // ---- stage A: BOLD GCN (aggregate-first, then transform+LN fused) ----
    init_deg_kernel<<<gN, b256, 0, stream>>>(dinv, Nn);
    hist_deg_kernel<<<gE, b256, 0, stream>>>(dst_b, eab, dinv, Ne);
    rsqrt_kernel<<<gN, b256, 0, stream>>>(dinv, Nn);
    hipMemsetAsync(cnt, 0, (size_t)Nn * 4, stream);
    hist_cnt_kernel<<<gE, b256, 0, stream>>>(dst_b, cnt, Ne);
    scan_kernel<<<dim3(1), dim3(1024), 0, stream>>>(cnt, rptr, cur, Nn);
    fill_kernel<<<gE, b256, 0, stream>>>(src_b, dst_b, eab, dinv, cur, ssrc, snrm, Ne);
    agg_kernel<<<dim3(Nn), b256, 0, stream>>>(x, rptr, ssrc, snrm, dinv, aggb);
    gemm_ln_kernel<0><<<gGemmN, b256, 0, stream>>>(
        aggb, HDIM, HDIM, Nn, Wb, bb, x, nullptr, gs, bs,
        nullptr, nullptr, x1);

    // ---- temporal edge-weight MLP (bf16 MFMA, fused GEMM + LN + dot) ----
    prep_w_kernel<<<dim3((256 * KAP + 255) / 256), b256, 0, stream>>>(W1, W1p);
    mlp_mfma_kernel<<<gGemmE, b256, 0, stream>>>(
        eat, W1p, b1, g1, be1, W2, b2, wtmp, Ne);

    // ---- stage B: temporal GCN + final LN (all fused in epilogue) ----
    init_deg_kernel<<<gN, b256, 0, stream>>>(dinv, Nn);
    hist_deg_kernel<<<gE, b256, 0, stream>>>(dst_t, wtmp, dinv, Ne);
    rsqrt_kernel<<<gN, b256, 0, stream>>>(dinv, Nn);
    hipMemsetAsync(cnt, 0, (size_t)Nn * 4, stream);
    hist_cnt_kernel<<<gE, b256, 0, stream>>>(dst_t, cnt, Ne);
    scan_kernel<<<dim3(1), dim3(1024), 0, stream>>>(cnt, rptr, cur, Nn);
    fill_kernel<<<gE, b256, 0, stream>>>(src_t, dst_t, wtmp, dinv, cur, ssrc, snrm, Ne);
    agg_kernel<<<dim3(Nn), b256, 0, stream>>>(x1, rptr, ssrc, snrm, dinv, aggb);
    gemm_ln_kernel<1><<<gGemmN, b256, 0, stream>>>(
        aggb, HDIM, HDIM, Nn, Wt, bt, x1, x, gt, btn,
        gs, bs, out);
}

// Round 3
// 1151.948 us; speedup vs baseline: 2.3163x; 1.3406x over previous
//
#include <hip/hip_runtime.h>

#define HDIM 256
#define KA 107
#define KAP 128

typedef short bf16x8 __attribute__((ext_vector_type(8)));
typedef float f32x4 __attribute__((ext_vector_type(4)));
typedef unsigned short ushort_t;

__device__ inline unsigned short f2bf(float f) {
    union { float f; unsigned u; } v; v.f = f;
    unsigned r = v.u + 0x7fff + ((v.u >> 16) & 1);
    return (unsigned short)(r >> 16);
}

__device__ inline unsigned cvt_pk_bf16(float a, float b) {
    unsigned r;
    asm("v_cvt_pk_bf16_f32 %0, %1, %2" : "=v"(r) : "v"(a), "v"(b));
    return r;   // low16 = bf16(a), high16 = bf16(b)
}

// ---------------- small kernels ----------------

__global__ void init_deg_kernel(float* deg, int n) {
    int i = blockIdx.x * 256 + threadIdx.x;
    if (i < n) deg[i] = 1.0f;   // self-loop weight
}

__global__ void hist_deg_kernel(const int* __restrict__ dst, const float* __restrict__ w,
                                float* deg, int ne) {
    int e = blockIdx.x * 256 + threadIdx.x;
    if (e < ne) atomicAdd(&deg[dst[e]], w[e]);
}

__global__ void rsqrt_kernel(float* deg, int n) {
    int i = blockIdx.x * 256 + threadIdx.x;
    if (i < n) { float d = deg[i]; deg[i] = d > 0.f ? rsqrtf(d) : 0.f; }
}

__global__ void hist_cnt_kernel(const int* __restrict__ dst, int* cnt, int ne) {
    int e = blockIdx.x * 256 + threadIdx.x;
    if (e < ne) atomicAdd(&cnt[dst[e]], 1);
}

// single-block exclusive scan over cnt[n] -> rptr[0..n], cur[i]=rptr[i]
__global__ __launch_bounds__(1024) void scan_kernel(const int* __restrict__ cnt,
                                                    int* __restrict__ rptr,
                                                    int* __restrict__ cur, int n) {
    const int per = (n + 1023) / 1024;
    const int tid = threadIdx.x;
    const int start = tid * per;
    const int end = min(start + per, n);
    int local = 0;
    for (int i = start; i < end; ++i) local += cnt[i];
    const int lane = tid & 63, wid = tid >> 6;
    int incl = local;
    for (int d = 1; d < 64; d <<= 1) { int m = __shfl_up(incl, d); if (lane >= d) incl += m; }
    __shared__ int wsum[16];
    if (lane == 63) wsum[wid] = incl;
    __syncthreads();
    if (tid < 16) {
        int v = wsum[tid];
        int iv = v;
        for (int d = 1; d < 16; d <<= 1) { int m = __shfl_up(iv, d, 16); if (tid >= d) iv += m; }
        wsum[tid] = iv - v;
    }
    __syncthreads();
    int run = (incl - local) + wsum[wid];
    for (int i = start; i < end; ++i) { int cc = cnt[i]; rptr[i] = run; cur[i] = run; run += cc; }
    if (start < n && end == n) rptr[n] = run;
}

__global__ void fill_kernel(const int* __restrict__ src, const int* __restrict__ dst,
                            const float* __restrict__ w, const float* __restrict__ dinv,
                            int* cur, int* __restrict__ ssrc, float* __restrict__ snrm, int ne) {
    int e = blockIdx.x * 256 + threadIdx.x;
    if (e < ne) {
        int s = src[e], d = dst[e];
        int pos = atomicAdd(&cur[d], 1);
        ssrc[pos] = s;
        snrm[pos] = dinv[s] * w[e] * dinv[d];
    }
}

// one wave per dst node, float4 per lane; bf16 output
__global__ __launch_bounds__(256) void agg_kernel(const float* __restrict__ X,
                                                  const int* __restrict__ rptr,
                                                  const int* __restrict__ ssrc,
                                                  const float* __restrict__ snrm,
                                                  const float* __restrict__ dinv,
                                                  ushort_t* __restrict__ out, int n) {
    const int v = blockIdx.x * 4 + (threadIdx.x >> 6);
    if (v >= n) return;
    const int lane = threadIdx.x & 63;
    const float dv = dinv[v];
    const float4 xv = *(const float4*)(X + (size_t)v * HDIM + lane * 4);
    float a0 = dv * dv * xv.x, a1 = dv * dv * xv.y;
    float a2 = dv * dv * xv.z, a3 = dv * dv * xv.w;
    const int b = rptr[v], e = rptr[v + 1];
    for (int i = b; i < e; ++i) {
        const int s = ssrc[i];
        const float nr = snrm[i];
        const float4 xs = *(const float4*)(X + (size_t)s * HDIM + lane * 4);
        a0 = fmaf(nr, xs.x, a0); a1 = fmaf(nr, xs.y, a1);
        a2 = fmaf(nr, xs.z, a2); a3 = fmaf(nr, xs.w, a3);
    }
    uint2 o;
    o.x = cvt_pk_bf16(a0, a1);
    o.y = cvt_pk_bf16(a2, a3);
    *(uint2*)(out + (size_t)v * HDIM + lane * 4) = o;
}

// ---------------- bf16 weight prep (generic, K -> KP padded) ----------------
__global__ void prep_w_kernel(const float* __restrict__ W, ushort_t* __restrict__ Wp,
                              int K, int KP) {
    int i = blockIdx.x * 256 + threadIdx.x;
    if (i < 256 * KP) {
        int n = i / KP, k = i - n * KP;
        Wp[i] = (k < K) ? f2bf(W[n * K + k]) : (ushort_t)0;
    }
}

// ---------------- edge MLP: bf16 MFMA + fused LN + dot(W2), C^T epilogue ----------------
// Lane (g=l>>4, c=l&15) holds rows m = rt*16+c, cols n = wv*64 + nt*16 + g*4 + reg.
__global__ __launch_bounds__(256) void mlp_mfma_kernel(
    const float* __restrict__ A,            // [M][107] f32
    const ushort_t* __restrict__ Wp,        // [256][128] bf16
    const float* __restrict__ b1v, const float* __restrict__ g1v,
    const float* __restrict__ be1v, const float* __restrict__ W2,
    const float* __restrict__ b2s, float* __restrict__ out, int M) {
    __shared__ ushort_t As[64][136];
    __shared__ float ps1[64][4], ps2[64][4], pd[64][4];
    const int tid = threadIdx.x;
    const int m0 = blockIdx.x * 64;
    const int l = tid & 63, wv = tid >> 6, g = l >> 4, c = l & 15;

    // zero-pad k in [107,128)
    for (int z = tid; z < 64 * 32; z += 256) {
        int r = z >> 5, k = 96 + (z & 31);
        if (k >= KA) As[r][k] = 0;
    }
    // stage A tile: 64*107 = 1712 float4, flat coalesced
    {
        const float* base = A + (size_t)m0 * KA;
        for (int it = 0; it < 7; ++it) {
            int idx = it * 256 + tid;
            if (idx < 1712) {
                float4 v4 = *(const float4*)(base + (size_t)idx * 4);
                const float* vv = (const float*)&v4;
                int e0 = idx * 4;
#pragma unroll
                for (int e = 0; e < 4; ++e) {
                    int ge = e0 + e;
                    int r = ge / KA;
                    int k = ge - r * KA;
                    As[r][k] = f2bf(vv[e]);
                }
            }
        }
    }
    __syncthreads();

    f32x4 acc[4][4];
#pragma unroll
    for (int rt = 0; rt < 4; ++rt)
#pragma unroll
        for (int nt = 0; nt < 4; ++nt) acc[rt][nt] = (f32x4){0.f, 0.f, 0.f, 0.f};

    const ushort_t* wb = Wp + (size_t)(wv * 64 + c) * KAP + g * 8;
#pragma unroll
    for (int ks = 0; ks < 4; ++ks) {
        bf16x8 af[4];
#pragma unroll
        for (int rt = 0; rt < 4; ++rt)
            af[rt] = *(const bf16x8*)&As[rt * 16 + c][ks * 32 + g * 8];
#pragma unroll
        for (int nt = 0; nt < 4; ++nt) {
            bf16x8 bfr = *(const bf16x8*)(wb + nt * 16 * KAP + ks * 32);
#pragma unroll
            for (int rt = 0; rt < 4; ++rt)
                acc[rt][nt] = __builtin_amdgcn_mfma_f32_16x16x32_bf16(bfr, af[rt], acc[rt][nt], 0, 0, 0);
        }
    }

    const int nb = wv * 64 + (g << 2);   // col base; + nt*16
    // pass 1: add bias, row sums
#pragma unroll
    for (int rt = 0; rt < 4; ++rt) {
        float s1 = 0.f, s2 = 0.f;
#pragma unroll
        for (int nt = 0; nt < 4; ++nt) {
            const float4 b4 = *(const float4*)(b1v + nb + nt * 16);
            f32x4 v = acc[rt][nt];
            v[0] += b4.x; v[1] += b4.y; v[2] += b4.z; v[3] += b4.w;
            acc[rt][nt] = v;
            s1 += v[0] + v[1] + v[2] + v[3];
            s2 += v[0] * v[0] + v[1] * v[1] + v[2] * v[2] + v[3] * v[3];
        }
        s1 += __shfl_xor(s1, 16); s1 += __shfl_xor(s1, 32);
        s2 += __shfl_xor(s2, 16); s2 += __shfl_xor(s2, 32);
        if (l < 16) { ps1[rt * 16 + c][wv] = s1; ps2[rt * 16 + c][wv] = s2; }
    }
    __syncthreads();
    // pass 2: LN + relu + dot(W2)
#pragma unroll
    for (int rt = 0; rt < 4; ++rt) {
        float4 p1 = *(const float4*)ps1[rt * 16 + c];
        float4 p2 = *(const float4*)ps2[rt * 16 + c];
        float s1 = p1.x + p1.y + p1.z + p1.w;
        float s2 = p2.x + p2.y + p2.z + p2.w;
        float mu = s1 * (1.f / HDIM);
        float var = s2 * (1.f / HDIM) - mu * mu;
        float rs = rsqrtf(var + 1e-5f);
        float dacc = 0.f;
#pragma unroll
        for (int nt = 0; nt < 4; ++nt) {
            const float4 g4 = *(const float4*)(g1v + nb + nt * 16);
            const float4 e4 = *(const float4*)(be1v + nb + nt * 16);
            const float4 w4 = *(const float4*)(W2 + nb + nt * 16);
            f32x4 v = acc[rt][nt];
            float y0 = fmaxf((v[0] - mu) * rs * g4.x + e4.x, 0.f);
            float y1 = fmaxf((v[1] - mu) * rs * g4.y + e4.y, 0.f);
            float y2 = fmaxf((v[2] - mu) * rs * g4.z + e4.z, 0.f);
            float y3 = fmaxf((v[3] - mu) * rs * g4.w + e4.w, 0.f);
            dacc = fmaf(y0, w4.x, dacc); dacc = fmaf(y1, w4.y, dacc);
            dacc = fmaf(y2, w4.z, dacc); dacc = fmaf(y3, w4.w, dacc);
        }
        dacc += __shfl_xor(dacc, 16); dacc += __shfl_xor(dacc, 32);
        if (l < 16) pd[rt * 16 + c][wv] = dacc;
    }
    __syncthreads();
    if (tid < 64) {
        float4 p = *(const float4*)pd[tid];
        int gr = m0 + tid;
        if (gr < M) out[gr] = p.x + p.y + p.z + p.w + b2s[0];
    }
}

// ---------------- node GEMM: bf16 MFMA, C^T epilogue, fused LN(s) ----------------
// MODE 0: out = relu(LN(A@W^T + bias + res; g1,b1))
// MODE 1: y = relu(LN(A@W^T + bias + res; g1,b1)); out = LN(y + orig; g2,b2)
template <int MODE>
__global__ __launch_bounds__(256) void gemm_node_kernel(
    const ushort_t* __restrict__ A,   // [M][256] bf16
    const ushort_t* __restrict__ Wp,  // [256][256] bf16
    const float* __restrict__ bias, const float* __restrict__ res,
    const float* __restrict__ orig,
    const float* __restrict__ g1v, const float* __restrict__ b1v,
    const float* __restrict__ g2v, const float* __restrict__ b2v,
    float* __restrict__ out, int M) {
    __shared__ ushort_t As[64][264];
    __shared__ float ps1[64][4], ps2[64][4], ps3[64][4], ps4[64][4];
    const int tid = threadIdx.x;
    const int m0 = blockIdx.x * 64;
    const int l = tid & 63, wv = tid >> 6, g = l >> 4, c = l & 15;

    // stage A: 64 rows x 256 bf16, 16B chunks, coalesced
    {
        const int r = tid >> 2, j = tid & 3;
        const ushort_t* gsrc = A + (size_t)(m0 + r) * HDIM;
        const bool ok = (m0 + r) < M;
#pragma unroll
        for (int i = 0; i < 8; ++i) {
            const int ci = i * 4 + j;
            bf16x8 v = (bf16x8){0,0,0,0,0,0,0,0};
            if (ok) v = *(const bf16x8*)(gsrc + ci * 8);
            *(bf16x8*)&As[r][ci * 8] = v;
        }
    }
    __syncthreads();

    f32x4 acc[4][4];
#pragma unroll
    for (int rt = 0; rt < 4; ++rt)
#pragma unroll
        for (int nt = 0; nt < 4; ++nt) acc[rt][nt] = (f32x4){0.f, 0.f, 0.f, 0.f};

    const ushort_t* wb = Wp + (size_t)(wv * 64 + c) * HDIM + g * 8;
#pragma unroll
    for (int ks = 0; ks < 8; ++ks) {
        bf16x8 af[4];
#pragma unroll
        for (int rt = 0; rt < 4; ++rt)
            af[rt] = *(const bf16x8*)&As[rt * 16 + c][ks * 32 + g * 8];
#pragma unroll
        for (int nt = 0; nt < 4; ++nt) {
            bf16x8 bfr = *(const bf16x8*)(wb + nt * 16 * HDIM + ks * 32);
#pragma unroll
            for (int rt = 0; rt < 4; ++rt)
                acc[rt][nt] = __builtin_amdgcn_mfma_f32_16x16x32_bf16(bfr, af[rt], acc[rt][nt], 0, 0, 0);
        }
    }

    const int nb = wv * 64 + (g << 2);
    // pass 1: v = acc + bias + res; row sums
#pragma unroll
    for (int rt = 0; rt < 4; ++rt) {
        const int m = m0 + rt * 16 + c;
        const bool vm = m < M;
        const float* rrow = res + (size_t)m * HDIM + nb;
        float s1 = 0.f, s2 = 0.f;
#pragma unroll
        for (int nt = 0; nt < 4; ++nt) {
            const float4 b4 = *(const float4*)(bias + nb + nt * 16);
            float4 r4 = {0.f, 0.f, 0.f, 0.f};
            if (vm) r4 = *(const float4*)(rrow + nt * 16);
            f32x4 v = acc[rt][nt];
            v[0] += b4.x + r4.x; v[1] += b4.y + r4.y;
            v[2] += b4.z + r4.z; v[3] += b4.w + r4.w;
            acc[rt][nt] = v;
            s1 += v[0] + v[1] + v[2] + v[3];
            s2 += v[0] * v[0] + v[1] * v[1] + v[2] * v[2] + v[3] * v[3];
        }
        s1 += __shfl_xor(s1, 16); s1 += __shfl_xor(s1, 32);
        s2 += __shfl_xor(s2, 16); s2 += __shfl_xor(s2, 32);
        if (l < 16) { ps1[rt * 16 + c][wv] = s1; ps2[rt * 16 + c][wv] = s2; }
    }
    __syncthreads();
    // pass 2: LN + relu (+ orig residual, second sums)
#pragma unroll
    for (int rt = 0; rt < 4; ++rt) {
        const int m = m0 + rt * 16 + c;
        const bool vm = m < M;
        float4 p1 = *(const float4*)ps1[rt * 16 + c];
        float4 p2 = *(const float4*)ps2[rt * 16 + c];
        float s1 = p1.x + p1.y + p1.z + p1.w;
        float s2 = p2.x + p2.y + p2.z + p2.w;
        float mu = s1 * (1.f / HDIM);
        float var = s2 * (1.f / HDIM) - mu * mu;
        float rs = rsqrtf(var + 1e-5f);
        if constexpr (MODE == 0) {
            float* orow = out + (size_t)m * HDIM + nb;
#pragma unroll
            for (int nt = 0; nt < 4; ++nt) {
                const float4 g4 = *(const float4*)(g1v + nb + nt * 16);
                const float4 e4 = *(const float4*)(b1v + nb + nt * 16);
                f32x4 v = acc[rt][nt];
                float4 o;
                o.x = fmaxf((v[0] - mu) * rs * g4.x + e4.x, 0.f);
                o.y = fmaxf((v[1] - mu) * rs * g4.y + e4.y, 0.f);
                o.z = fmaxf((v[2] - mu) * rs * g4.z + e4.z, 0.f);
                o.w = fmaxf((v[3] - mu) * rs * g4.w + e4.w, 0.f);
                if (vm) *(float4*)(orow + nt * 16) = o;
            }
        } else {
            const float* grow = orig + (size_t)m * HDIM + nb;
            float t1 = 0.f, t2 = 0.f;
#pragma unroll
            for (int nt = 0; nt < 4; ++nt) {
                const float4 g4 = *(const float4*)(g1v + nb + nt * 16);
                const float4 e4 = *(const float4*)(b1v + nb + nt * 16);
                float4 o4 = {0.f, 0.f, 0.f, 0.f};
                if (vm) o4 = *(const float4*)(grow + nt * 16);
                f32x4 v = acc[rt][nt];
                f32x4 u;
                u[0] = fmaxf((v[0] - mu) * rs * g4.x + e4.x, 0.f) + o4.x;
                u[1] = fmaxf((v[1] - mu) * rs * g4.y + e4.y, 0.f) + o4.y;
                u[2] = fmaxf((v[2] - mu) * rs * g4.z + e4.z, 0.f) + o4.z;
                u[3] = fmaxf((v[3] - mu) * rs * g4.w + e4.w, 0.f) + o4.w;
                acc[rt][nt] = u;
                t1 += u[0] + u[1] + u[2] + u[3];
                t2 += u[0] * u[0] + u[1] * u[1] + u[2] * u[2] + u[3] * u[3];
            }
            t1 += __shfl_xor(t1, 16); t1 += __shfl_xor(t1, 32);
            t2 += __shfl_xor(t2, 16); t2 += __shfl_xor(t2, 32);
            if (l < 16) { ps3[rt * 16 + c][wv] = t1; ps4[rt * 16 + c][wv] = t2; }
        }
    }
    if constexpr (MODE == 1) {
        __syncthreads();
#pragma unroll
        for (int rt = 0; rt < 4; ++rt) {
            const int m = m0 + rt * 16 + c;
            const bool vm = m < M;
            float4 p1 = *(const float4*)ps3[rt * 16 + c];
            float4 p2 = *(const float4*)ps4[rt * 16 + c];
            float s1 = p1.x + p1.y + p1.z + p1.w;
            float s2 = p2.x + p2.y + p2.z + p2.w;
            float mu2 = s1 * (1.f / HDIM);
            float var2 = s2 * (1.f / HDIM) - mu2 * mu2;
            float rs2 = rsqrtf(var2 + 1e-5f);
            float* orow = out + (size_t)m * HDIM + nb;
#pragma unroll
            for (int nt = 0; nt < 4; ++nt) {
                const float4 g4 = *(const float4*)(g2v + nb + nt * 16);
                const float4 e4 = *(const float4*)(b2v + nb + nt * 16);
                f32x4 u = acc[rt][nt];
                float4 o;
                o.x = (u[0] - mu2) * rs2 * g4.x + e4.x;
                o.y = (u[1] - mu2) * rs2 * g4.y + e4.y;
                o.z = (u[2] - mu2) * rs2 * g4.z + e4.z;
                o.w = (u[3] - mu2) * rs2 * g4.w + e4.w;
                if (vm) *(float4*)(orow + nt * 16) = o;
            }
        }
    }
}

// ---------------- launch ----------------

extern "C" void kernel_launch(void* const* d_in, const int* in_sizes, int n_in,
                              void* d_out, int out_size, void* d_ws, size_t ws_size,
                              hipStream_t stream) {
    const float* x    = (const float*)d_in[0];
    const int*   eib  = (const int*)d_in[1];
    const float* eab  = (const float*)d_in[2];
    const int*   eit  = (const int*)d_in[3];
    const float* eat  = (const float*)d_in[4];
    const float* Wb   = (const float*)d_in[5];
    const float* bb   = (const float*)d_in[6];
    const float* Wt   = (const float*)d_in[7];
    const float* bt   = (const float*)d_in[8];
    const float* W1   = (const float*)d_in[9];
    const float* b1   = (const float*)d_in[10];
    const float* g1   = (const float*)d_in[11];
    const float* be1  = (const float*)d_in[12];
    const float* W2   = (const float*)d_in[13];
    const float* b2   = (const float*)d_in[14];
    const float* gs   = (const float*)d_in[15];
    const float* bs   = (const float*)d_in[16];
    const float* gt   = (const float*)d_in[17];
    const float* btn  = (const float*)d_in[18];

    const int Nn = in_sizes[0] / HDIM;     // 50000
    const int Ne = in_sizes[2];            // 800000

    const int* src_b = eib;  const int* dst_b = eib + Ne;
    const int* src_t = eit;  const int* dst_t = eit + Ne;

    char* w = (char*)d_ws;
    float*    x1   = (float*)w;    w += (size_t)Nn * HDIM * 4;
    ushort_t* aggb = (ushort_t*)w; w += (size_t)Nn * HDIM * 2;
    float*    wtmp = (float*)w;    w += (size_t)Ne * 4;
    float*    dinv = (float*)w;    w += (size_t)Nn * 4;
    int*      cnt  = (int*)w;      w += (size_t)Nn * 4;
    int*      rptr = (int*)w;      w += (size_t)(Nn + 4) * 4;
    int*      cur  = (int*)w;      w += (size_t)Nn * 4;
    int*      ssrc = (int*)w;      w += (size_t)Ne * 4;
    float*    snrm = (float*)w;    w += (size_t)Ne * 4;
    ushort_t* W1p  = (ushort_t*)w; w += (size_t)256 * KAP * 2;
    ushort_t* Wbp  = (ushort_t*)w; w += (size_t)256 * 256 * 2;
    ushort_t* Wtp  = (ushort_t*)w; w += (size_t)256 * 256 * 2;

    float* out = (float*)d_out;
    dim3 b256(256);
    dim3 gN((Nn + 255) / 256), gE((Ne + 255) / 256);
    dim3 gAgg((Nn + 3) / 4);
    dim3 gGemmN((Nn + 63) / 64), gGemmE((Ne + 63) / 64);

    // ---- weight prep (bf16) ----
    prep_w_kernel<<<dim3((256 * KAP + 255) / 256), b256, 0, stream>>>(W1, W1p, KA, KAP);
    prep_w_kernel<<<dim3((256 * 256 + 255) / 256), b256, 0, stream>>>(Wb, Wbp, 256, 256);
    prep_w_kernel<<<dim3((256 * 256 + 255) / 256), b256, 0, stream>>>(Wt, Wtp, 256, 256);

    // ---- stage A: BOLD GCN ----
    init_deg_kernel<<<gN, b256, 0, stream>>>(dinv, Nn);
    hist_deg_kernel<<<gE, b256, 0, stream>>>(dst_b, eab, dinv, Ne);
    rsqrt_kernel<<<gN, b256, 0, stream>>>(dinv, Nn);
    hipMemsetAsync(cnt, 0, (size_t)Nn * 4, stream);
    hist_cnt_kernel<<<gE, b256, 0, stream>>>(dst_b, cnt, Ne);
    scan_kernel<<<dim3(1), dim3(1024), 0, stream>>>(cnt, rptr, cur, Nn);
    fill_kernel<<<gE, b256, 0, stream>>>(src_b, dst_b, eab, dinv, cur, ssrc, snrm, Ne);
    agg_kernel<<<gAgg, b256, 0, stream>>>(x, rptr, ssrc, snrm, dinv, aggb, Nn);
    gemm_node_kernel<0><<<gGemmN, b256, 0, stream>>>(
        aggb, Wbp, bb, x, nullptr, gs, bs, nullptr, nullptr, x1, Nn);

    // ---- temporal edge-weight MLP ----
    mlp_mfma_kernel<<<gGemmE, b256, 0, stream>>>(
        eat, W1p, b1, g1, be1, W2, b2, wtmp, Ne);

    // ---- stage B: temporal GCN + final LN ----
    init_deg_kernel<<<gN, b256, 0, stream>>>(dinv, Nn);
    hist_deg_kernel<<<gE, b256, 0, stream>>>(dst_t, wtmp, dinv, Ne);
    rsqrt_kernel<<<gN, b256, 0, stream>>>(dinv, Nn);
    hipMemsetAsync(cnt, 0, (size_t)Nn * 4, stream);
    hist_cnt_kernel<<<gE, b256, 0, stream>>>(dst_t, cnt, Ne);
    scan_kernel<<<dim3(1), dim3(1024), 0, stream>>>(cnt, rptr, cur, Nn);
    fill_kernel<<<gE, b256, 0, stream>>>(src_t, dst_t, wtmp, dinv, cur, ssrc, snrm, Ne);
    agg_kernel<<<gAgg, b256, 0, stream>>>(x1, rptr, ssrc, snrm, dinv, aggb, Nn);
    gemm_node_kernel<1><<<gGemmN, b256, 0, stream>>>(
        aggb, Wtp, bt, x1, x, gt, btn, gs, bs, out, Nn);
}

// Round 4
// 1005.951 us; speedup vs baseline: 2.6524x; 1.1451x over previous
//
#include <hip/hip_runtime.h>

#define HDIM 256
#define KA 107
#define KAP 128

typedef short bf16x8 __attribute__((ext_vector_type(8)));
typedef float f32x4 __attribute__((ext_vector_type(4)));
typedef unsigned short ushort_t;

__device__ inline unsigned short f2bf(float f) {
    union { float f; unsigned u; } v; v.f = f;
    unsigned r = v.u + 0x7fff + ((v.u >> 16) & 1);
    return (unsigned short)(r >> 16);
}

__device__ inline unsigned cvt_pk_bf16(float a, float b) {
    unsigned r;
    asm("v_cvt_pk_bf16_f32 %0, %1, %2" : "=v"(r) : "v"(a), "v"(b));
    return r;   // low16 = bf16(a), high16 = bf16(b)
}

__device__ inline float bf_lo(unsigned u) { union { unsigned v; float f; } x; x.v = u << 16; return x.f; }
__device__ inline float bf_hi(unsigned u) { union { unsigned v; float f; } x; x.v = u & 0xffff0000u; return x.f; }

// ---------------- small kernels ----------------

__global__ void init_deg_kernel(float* deg, int n) {
    int i = blockIdx.x * 256 + threadIdx.x;
    if (i < n) deg[i] = 1.0f;   // self-loop weight
}

__global__ void hist_deg_kernel(const int* __restrict__ dst, const float* __restrict__ w,
                                float* deg, int ne) {
    int e = blockIdx.x * 256 + threadIdx.x;
    if (e < ne) atomicAdd(&deg[dst[e]], w[e]);
}

__global__ void rsqrt_kernel(float* deg, int n) {
    int i = blockIdx.x * 256 + threadIdx.x;
    if (i < n) { float d = deg[i]; deg[i] = d > 0.f ? rsqrtf(d) : 0.f; }
}

__global__ void hist_cnt_kernel(const int* __restrict__ dst, int* cnt, int ne) {
    int e = blockIdx.x * 256 + threadIdx.x;
    if (e < ne) atomicAdd(&cnt[dst[e]], 1);
}

// f32 -> bf16 mirror (float4 -> uint2)
__global__ void f32_to_bf16_kernel(const float* __restrict__ in, ushort_t* __restrict__ out, int n4) {
    int i = blockIdx.x * 256 + threadIdx.x;
    if (i < n4) {
        float4 v = ((const float4*)in)[i];
        uint2 o;
        o.x = cvt_pk_bf16(v.x, v.y);
        o.y = cvt_pk_bf16(v.z, v.w);
        ((uint2*)out)[i] = o;
    }
}

// single-block exclusive scan over cnt[n] -> rptr[0..n], cur[i]=rptr[i]
__global__ __launch_bounds__(1024) void scan_kernel(const int* __restrict__ cnt,
                                                    int* __restrict__ rptr,
                                                    int* __restrict__ cur, int n) {
    const int per = (n + 1023) / 1024;
    const int tid = threadIdx.x;
    const int start = tid * per;
    const int end = min(start + per, n);
    int local = 0;
    for (int i = start; i < end; ++i) local += cnt[i];
    const int lane = tid & 63, wid = tid >> 6;
    int incl = local;
    for (int d = 1; d < 64; d <<= 1) { int m = __shfl_up(incl, d); if (lane >= d) incl += m; }
    __shared__ int wsum[16];
    if (lane == 63) wsum[wid] = incl;
    __syncthreads();
    if (tid < 16) {
        int v = wsum[tid];
        int iv = v;
        for (int d = 1; d < 16; d <<= 1) { int m = __shfl_up(iv, d, 16); if (tid >= d) iv += m; }
        wsum[tid] = iv - v;
    }
    __syncthreads();
    int run = (incl - local) + wsum[wid];
    for (int i = start; i < end; ++i) { int cc = cnt[i]; rptr[i] = run; cur[i] = run; run += cc; }
    if (start < n && end == n) rptr[n] = run;
}

__global__ void fill_kernel(const int* __restrict__ src, const int* __restrict__ dst,
                            const float* __restrict__ w, const float* __restrict__ dinv,
                            int* cur, int* __restrict__ ssrc, float* __restrict__ snrm, int ne) {
    int e = blockIdx.x * 256 + threadIdx.x;
    if (e < ne) {
        int s = src[e], d = dst[e];
        int pos = atomicAdd(&cur[d], 1);
        ssrc[pos] = s;
        snrm[pos] = dinv[s] * w[e] * dinv[d];
    }
}

// one wave per dst node; bf16 gather rows, f32 accumulate, bf16 out
__global__ __launch_bounds__(256) void agg_kernel(const ushort_t* __restrict__ Xb,
                                                  const int* __restrict__ rptr,
                                                  const int* __restrict__ ssrc,
                                                  const float* __restrict__ snrm,
                                                  const float* __restrict__ dinv,
                                                  ushort_t* __restrict__ out, int n) {
    const int v = blockIdx.x * 4 + (threadIdx.x >> 6);
    if (v >= n) return;
    const int lane = threadIdx.x & 63;
    const float dv = dinv[v];
    const uint2 xv = *(const uint2*)(Xb + (size_t)v * HDIM + lane * 4);
    const float dv2 = dv * dv;
    float a0 = dv2 * bf_lo(xv.x), a1 = dv2 * bf_hi(xv.x);
    float a2 = dv2 * bf_lo(xv.y), a3 = dv2 * bf_hi(xv.y);
    const int b = rptr[v], e = rptr[v + 1];
    int i = b;
    uint2 pv; float pn = 0.f;
    if (i < e) {
        int s = ssrc[i]; pn = snrm[i];
        pv = *(const uint2*)(Xb + (size_t)s * HDIM + lane * 4);
    }
    while (i < e) {
        uint2 cvv = pv; float cn = pn;
        ++i;
        if (i < e) {   // prefetch next row while consuming current
            int s = ssrc[i]; pn = snrm[i];
            pv = *(const uint2*)(Xb + (size_t)s * HDIM + lane * 4);
        }
        a0 = fmaf(cn, bf_lo(cvv.x), a0); a1 = fmaf(cn, bf_hi(cvv.x), a1);
        a2 = fmaf(cn, bf_lo(cvv.y), a2); a3 = fmaf(cn, bf_hi(cvv.y), a3);
    }
    uint2 o;
    o.x = cvt_pk_bf16(a0, a1);
    o.y = cvt_pk_bf16(a2, a3);
    *(uint2*)(out + (size_t)v * HDIM + lane * 4) = o;
}

// ---------------- bf16 weight prep (generic, K -> KP padded) ----------------
__global__ void prep_w_kernel(const float* __restrict__ W, ushort_t* __restrict__ Wp,
                              int K, int KP) {
    int i = blockIdx.x * 256 + threadIdx.x;
    if (i < 256 * KP) {
        int n = i / KP, k = i - n * KP;
        Wp[i] = (k < K) ? f2bf(W[n * K + k]) : (ushort_t)0;
    }
}

// ---------------- edge MLP: persistent grid-stride, dbuf LDS, T14 split ----------------
// Lane (g=l>>4, c=l&15) holds rows m = rt*16+c, cols n = wv*64 + nt*16 + g*4 + reg.
__global__ __launch_bounds__(256) void mlp_mfma_kernel(
    const float* __restrict__ A,            // [M][107] f32
    const ushort_t* __restrict__ Wp,        // [256][128] bf16
    const float* __restrict__ b1v, const float* __restrict__ g1v,
    const float* __restrict__ be1v, const float* __restrict__ W2,
    const float* __restrict__ b2s, float* __restrict__ out,
    int M, int ntiles) {
    __shared__ ushort_t As[2][64][136];
    __shared__ float ps1[64][4], ps2[64][4], pd[64][4];
    const int tid = threadIdx.x;
    const int l = tid & 63, wv = tid >> 6, g = l >> 4, c = l & 15;
    const float b2sc = b2s[0];

    // zero k-pad [107,128) for BOTH buffers (never touched by staging)
    for (int z = tid; z < 2 * 64 * 21; z += 256) {
        int buf = z / (64 * 21);
        int rem = z - buf * 64 * 21;
        int r = rem / 21;
        int k = 107 + (rem - r * 21);
        As[buf][r][k] = 0;
    }

    float4 sreg[7];
    const size_t totElems = (size_t)M * KA;

    // ---- prologue: load + write tile t0 into buf 0 ----
    const int t0 = blockIdx.x;
    if (t0 < ntiles) {
        const size_t base = (size_t)t0 * (64 * KA);
        const float* p = A + base;
#pragma unroll
        for (int it = 0; it < 7; ++it) {
            int idx = it * 256 + tid;
            if (idx < 1712 && base + (size_t)idx * 4 + 4 <= totElems)
                sreg[it] = *(const float4*)(p + (size_t)idx * 4);
        }
#pragma unroll
        for (int it = 0; it < 7; ++it) {
            int idx = it * 256 + tid;
            if (idx < 1712 && base + (size_t)idx * 4 + 4 <= totElems) {
                const float* vv = (const float*)&sreg[it];
                int e0 = idx * 4;
#pragma unroll
                for (int e = 0; e < 4; ++e) {
                    int ge = e0 + e;
                    int rr = ge / KA;
                    int k = ge - rr * KA;
                    As[0][rr][k] = f2bf(vv[e]);
                }
            }
        }
    }
    __syncthreads();

    int cur = 0;
    for (int t = t0; t < ntiles; t += gridDim.x) {
        const int tn = t + gridDim.x;
        const bool have_next = tn < ntiles;
        const size_t nbase = (size_t)tn * (64 * KA);
        // (A) issue next tile's global loads early (consumed after pass2)
        if (have_next) {
            const float* p = A + nbase;
#pragma unroll
            for (int it = 0; it < 7; ++it) {
                int idx = it * 256 + tid;
                if (idx < 1712 && nbase + (size_t)idx * 4 + 4 <= totElems)
                    sreg[it] = *(const float4*)(p + (size_t)idx * 4);
            }
        }

        // (B) MFMA on As[cur]
        f32x4 acc[4][4];
#pragma unroll
        for (int rt = 0; rt < 4; ++rt)
#pragma unroll
            for (int nt = 0; nt < 4; ++nt) acc[rt][nt] = (f32x4){0.f, 0.f, 0.f, 0.f};
        const ushort_t* wb = Wp + (size_t)(wv * 64 + c) * KAP + g * 8;
#pragma unroll
        for (int ks = 0; ks < 4; ++ks) {
            bf16x8 af[4];
#pragma unroll
            for (int rt = 0; rt < 4; ++rt)
                af[rt] = *(const bf16x8*)&As[cur][rt * 16 + c][ks * 32 + g * 8];
#pragma unroll
            for (int nt = 0; nt < 4; ++nt) {
                bf16x8 bfr = *(const bf16x8*)(wb + nt * 16 * KAP + ks * 32);
#pragma unroll
                for (int rt = 0; rt < 4; ++rt)
                    acc[rt][nt] = __builtin_amdgcn_mfma_f32_16x16x32_bf16(bfr, af[rt], acc[rt][nt], 0, 0, 0);
            }
        }

        const int nb = wv * 64 + (g << 2);
        const int m0 = t * 64;
        // (C) pass 1: bias + row sums
#pragma unroll
        for (int rt = 0; rt < 4; ++rt) {
            float s1 = 0.f, s2 = 0.f;
#pragma unroll
            for (int nt = 0; nt < 4; ++nt) {
                const float4 b4 = *(const float4*)(b1v + nb + nt * 16);
                f32x4 v = acc[rt][nt];
                v[0] += b4.x; v[1] += b4.y; v[2] += b4.z; v[3] += b4.w;
                acc[rt][nt] = v;
                s1 += v[0] + v[1] + v[2] + v[3];
                s2 += v[0] * v[0] + v[1] * v[1] + v[2] * v[2] + v[3] * v[3];
            }
            s1 += __shfl_xor(s1, 16); s1 += __shfl_xor(s1, 32);
            s2 += __shfl_xor(s2, 16); s2 += __shfl_xor(s2, 32);
            if (l < 16) { ps1[rt * 16 + c][wv] = s1; ps2[rt * 16 + c][wv] = s2; }
        }
        __syncthreads();   // barrier 1: ps published
        // (D) pass 2: LN + relu + dot(W2) -> pd
#pragma unroll
        for (int rt = 0; rt < 4; ++rt) {
            float4 p1 = *(const float4*)ps1[rt * 16 + c];
            float4 p2 = *(const float4*)ps2[rt * 16 + c];
            float s1 = p1.x + p1.y + p1.z + p1.w;
            float s2 = p2.x + p2.y + p2.z + p2.w;
            float mu = s1 * (1.f / HDIM);
            float var = s2 * (1.f / HDIM) - mu * mu;
            float rs = rsqrtf(var + 1e-5f);
            float dacc = 0.f;
#pragma unroll
            for (int nt = 0; nt < 4; ++nt) {
                const float4 g4 = *(const float4*)(g1v + nb + nt * 16);
                const float4 e4 = *(const float4*)(be1v + nb + nt * 16);
                const float4 w4 = *(const float4*)(W2 + nb + nt * 16);
                f32x4 v = acc[rt][nt];
                float y0 = fmaxf((v[0] - mu) * rs * g4.x + e4.x, 0.f);
                float y1 = fmaxf((v[1] - mu) * rs * g4.y + e4.y, 0.f);
                float y2 = fmaxf((v[2] - mu) * rs * g4.z + e4.z, 0.f);
                float y3 = fmaxf((v[3] - mu) * rs * g4.w + e4.w, 0.f);
                dacc = fmaf(y0, w4.x, dacc); dacc = fmaf(y1, w4.y, dacc);
                dacc = fmaf(y2, w4.z, dacc); dacc = fmaf(y3, w4.w, dacc);
            }
            dacc += __shfl_xor(dacc, 16); dacc += __shfl_xor(dacc, 32);
            if (l < 16) pd[rt * 16 + c][wv] = dacc;
        }
        // (E) write next buffer (other buffer: no reader until after barrier 2)
        if (have_next) {
#pragma unroll
            for (int it = 0; it < 7; ++it) {
                int idx = it * 256 + tid;
                if (idx < 1712 && nbase + (size_t)idx * 4 + 4 <= totElems) {
                    const float* vv = (const float*)&sreg[it];
                    int e0 = idx * 4;
#pragma unroll
                    for (int e = 0; e < 4; ++e) {
                        int ge = e0 + e;
                        int rr = ge / KA;
                        int k = ge - rr * KA;
                        As[cur ^ 1][rr][k] = f2bf(vv[e]);
                    }
                }
            }
        }
        __syncthreads();   // barrier 2: pd published + As[cur^1] complete
        // (F) out store for tile t
        if (tid < 64) {
            float4 p = *(const float4*)pd[tid];
            int gr = m0 + tid;
            if (gr < M) out[gr] = p.x + p.y + p.z + p.w + b2sc;
        }
        cur ^= 1;
    }
}

// ---------------- node GEMM: bf16 MFMA, C^T epilogue, fused LN(s) ----------------
// MODE 0: out = relu(LN(A@W^T + bias + res; g1,b1)); also writes bf16 mirror out_bf
// MODE 1: y = relu(LN(A@W^T + bias + res; g1,b1)); out = LN(y + orig; g2,b2)
template <int MODE>
__global__ __launch_bounds__(256) void gemm_node_kernel(
    const ushort_t* __restrict__ A,   // [M][256] bf16
    const ushort_t* __restrict__ Wp,  // [256][256] bf16
    const float* __restrict__ bias, const float* __restrict__ res,
    const float* __restrict__ orig,
    const float* __restrict__ g1v, const float* __restrict__ b1v,
    const float* __restrict__ g2v, const float* __restrict__ b2v,
    float* __restrict__ out, ushort_t* __restrict__ out_bf, int M) {
    __shared__ ushort_t As[64][264];
    __shared__ float ps1[64][4], ps2[64][4], ps3[64][4], ps4[64][4];
    const int tid = threadIdx.x;
    const int m0 = blockIdx.x * 64;
    const int l = tid & 63, wv = tid >> 6, g = l >> 4, c = l & 15;

    {
        const int r = tid >> 2, j = tid & 3;
        const ushort_t* gsrc = A + (size_t)(m0 + r) * HDIM;
        const bool ok = (m0 + r) < M;
#pragma unroll
        for (int i = 0; i < 8; ++i) {
            const int ci = i * 4 + j;
            bf16x8 v = (bf16x8){0,0,0,0,0,0,0,0};
            if (ok) v = *(const bf16x8*)(gsrc + ci * 8);
            *(bf16x8*)&As[r][ci * 8] = v;
        }
    }
    __syncthreads();

    f32x4 acc[4][4];
#pragma unroll
    for (int rt = 0; rt < 4; ++rt)
#pragma unroll
        for (int nt = 0; nt < 4; ++nt) acc[rt][nt] = (f32x4){0.f, 0.f, 0.f, 0.f};

    const ushort_t* wb = Wp + (size_t)(wv * 64 + c) * HDIM + g * 8;
#pragma unroll
    for (int ks = 0; ks < 8; ++ks) {
        bf16x8 af[4];
#pragma unroll
        for (int rt = 0; rt < 4; ++rt)
            af[rt] = *(const bf16x8*)&As[rt * 16 + c][ks * 32 + g * 8];
#pragma unroll
        for (int nt = 0; nt < 4; ++nt) {
            bf16x8 bfr = *(const bf16x8*)(wb + nt * 16 * HDIM + ks * 32);
#pragma unroll
            for (int rt = 0; rt < 4; ++rt)
                acc[rt][nt] = __builtin_amdgcn_mfma_f32_16x16x32_bf16(bfr, af[rt], acc[rt][nt], 0, 0, 0);
        }
    }

    const int nb = wv * 64 + (g << 2);
#pragma unroll
    for (int rt = 0; rt < 4; ++rt) {
        const int m = m0 + rt * 16 + c;
        const bool vm = m < M;
        const float* rrow = res + (size_t)m * HDIM + nb;
        float s1 = 0.f, s2 = 0.f;
#pragma unroll
        for (int nt = 0; nt < 4; ++nt) {
            const float4 b4 = *(const float4*)(bias + nb + nt * 16);
            float4 r4 = {0.f, 0.f, 0.f, 0.f};
            if (vm) r4 = *(const float4*)(rrow + nt * 16);
            f32x4 v = acc[rt][nt];
            v[0] += b4.x + r4.x; v[1] += b4.y + r4.y;
            v[2] += b4.z + r4.z; v[3] += b4.w + r4.w;
            acc[rt][nt] = v;
            s1 += v[0] + v[1] + v[2] + v[3];
            s2 += v[0] * v[0] + v[1] * v[1] + v[2] * v[2] + v[3] * v[3];
        }
        s1 += __shfl_xor(s1, 16); s1 += __shfl_xor(s1, 32);
        s2 += __shfl_xor(s2, 16); s2 += __shfl_xor(s2, 32);
        if (l < 16) { ps1[rt * 16 + c][wv] = s1; ps2[rt * 16 + c][wv] = s2; }
    }
    __syncthreads();
#pragma unroll
    for (int rt = 0; rt < 4; ++rt) {
        const int m = m0 + rt * 16 + c;
        const bool vm = m < M;
        float4 p1 = *(const float4*)ps1[rt * 16 + c];
        float4 p2 = *(const float4*)ps2[rt * 16 + c];
        float s1 = p1.x + p1.y + p1.z + p1.w;
        float s2 = p2.x + p2.y + p2.z + p2.w;
        float mu = s1 * (1.f / HDIM);
        float var = s2 * (1.f / HDIM) - mu * mu;
        float rs = rsqrtf(var + 1e-5f);
        if constexpr (MODE == 0) {
            float* orow = out + (size_t)m * HDIM + nb;
            ushort_t* obrow = out_bf + (size_t)m * HDIM + nb;
#pragma unroll
            for (int nt = 0; nt < 4; ++nt) {
                const float4 g4 = *(const float4*)(g1v + nb + nt * 16);
                const float4 e4 = *(const float4*)(b1v + nb + nt * 16);
                f32x4 v = acc[rt][nt];
                float4 o;
                o.x = fmaxf((v[0] - mu) * rs * g4.x + e4.x, 0.f);
                o.y = fmaxf((v[1] - mu) * rs * g4.y + e4.y, 0.f);
                o.z = fmaxf((v[2] - mu) * rs * g4.z + e4.z, 0.f);
                o.w = fmaxf((v[3] - mu) * rs * g4.w + e4.w, 0.f);
                if (vm) {
                    *(float4*)(orow + nt * 16) = o;
                    uint2 ob;
                    ob.x = cvt_pk_bf16(o.x, o.y);
                    ob.y = cvt_pk_bf16(o.z, o.w);
                    *(uint2*)(obrow + nt * 16) = ob;
                }
            }
        } else {
            const float* grow = orig + (size_t)m * HDIM + nb;
            float t1 = 0.f, t2 = 0.f;
#pragma unroll
            for (int nt = 0; nt < 4; ++nt) {
                const float4 g4 = *(const float4*)(g1v + nb + nt * 16);
                const float4 e4 = *(const float4*)(b1v + nb + nt * 16);
                float4 o4 = {0.f, 0.f, 0.f, 0.f};
                if (vm) o4 = *(const float4*)(grow + nt * 16);
                f32x4 v = acc[rt][nt];
                f32x4 u;
                u[0] = fmaxf((v[0] - mu) * rs * g4.x + e4.x, 0.f) + o4.x;
                u[1] = fmaxf((v[1] - mu) * rs * g4.y + e4.y, 0.f) + o4.y;
                u[2] = fmaxf((v[2] - mu) * rs * g4.z + e4.z, 0.f) + o4.z;
                u[3] = fmaxf((v[3] - mu) * rs * g4.w + e4.w, 0.f) + o4.w;
                acc[rt][nt] = u;
                t1 += u[0] + u[1] + u[2] + u[3];
                t2 += u[0] * u[0] + u[1] * u[1] + u[2] * u[2] + u[3] * u[3];
            }
            t1 += __shfl_xor(t1, 16); t1 += __shfl_xor(t1, 32);
            t2 += __shfl_xor(t2, 16); t2 += __shfl_xor(t2, 32);
            if (l < 16) { ps3[rt * 16 + c][wv] = t1; ps4[rt * 16 + c][wv] = t2; }
        }
    }
    if constexpr (MODE == 1) {
        __syncthreads();
#pragma unroll
        for (int rt = 0; rt < 4; ++rt) {
            const int m = m0 + rt * 16 + c;
            const bool vm = m < M;
            float4 p1 = *(const float4*)ps3[rt * 16 + c];
            float4 p2 = *(const float4*)ps4[rt * 16 + c];
            float s1 = p1.x + p1.y + p1.z + p1.w;
            float s2 = p2.x + p2.y + p2.z + p2.w;
            float mu2 = s1 * (1.f / HDIM);
            float var2 = s2 * (1.f / HDIM) - mu2 * mu2;
            float rs2 = rsqrtf(var2 + 1e-5f);
            float* orow = out + (size_t)m * HDIM + nb;
#pragma unroll
            for (int nt = 0; nt < 4; ++nt) {
                const float4 g4 = *(const float4*)(g2v + nb + nt * 16);
                const float4 e4 = *(const float4*)(b2v + nb + nt * 16);
                f32x4 u = acc[rt][nt];
                float4 o;
                o.x = (u[0] - mu2) * rs2 * g4.x + e4.x;
                o.y = (u[1] - mu2) * rs2 * g4.y + e4.y;
                o.z = (u[2] - mu2) * rs2 * g4.z + e4.z;
                o.w = (u[3] - mu2) * rs2 * g4.w + e4.w;
                if (vm) *(float4*)(orow + nt * 16) = o;
            }
        }
    }
}

// ---------------- launch ----------------

extern "C" void kernel_launch(void* const* d_in, const int* in_sizes, int n_in,
                              void* d_out, int out_size, void* d_ws, size_t ws_size,
                              hipStream_t stream) {
    const float* x    = (const float*)d_in[0];
    const int*   eib  = (const int*)d_in[1];
    const float* eab  = (const float*)d_in[2];
    const int*   eit  = (const int*)d_in[3];
    const float* eat  = (const float*)d_in[4];
    const float* Wb   = (const float*)d_in[5];
    const float* bb   = (const float*)d_in[6];
    const float* Wt   = (const float*)d_in[7];
    const float* bt   = (const float*)d_in[8];
    const float* W1   = (const float*)d_in[9];
    const float* b1   = (const float*)d_in[10];
    const float* g1   = (const float*)d_in[11];
    const float* be1  = (const float*)d_in[12];
    const float* W2   = (const float*)d_in[13];
    const float* b2   = (const float*)d_in[14];
    const float* gs   = (const float*)d_in[15];
    const float* bs   = (const float*)d_in[16];
    const float* gt   = (const float*)d_in[17];
    const float* btn  = (const float*)d_in[18];

    const int Nn = in_sizes[0] / HDIM;     // 50000
    const int Ne = in_sizes[2];            // 800000

    const int* src_b = eib;  const int* dst_b = eib + Ne;
    const int* src_t = eit;  const int* dst_t = eit + Ne;

    char* w = (char*)d_ws;
    float*    x1   = (float*)w;    w += (size_t)Nn * HDIM * 4;
    ushort_t* aggb = (ushort_t*)w; w += (size_t)Nn * HDIM * 2;
    ushort_t* xb   = (ushort_t*)w; w += (size_t)Nn * HDIM * 2;
    ushort_t* x1b  = (ushort_t*)w; w += (size_t)Nn * HDIM * 2;
    float*    wtmp = (float*)w;    w += (size_t)Ne * 4;
    float*    dinv = (float*)w;    w += (size_t)Nn * 4;
    int*      cnt  = (int*)w;      w += (size_t)Nn * 4;
    int*      rptr = (int*)w;      w += (size_t)(Nn + 4) * 4;
    int*      cur  = (int*)w;      w += (size_t)Nn * 4;
    int*      ssrc = (int*)w;      w += (size_t)Ne * 4;
    float*    snrm = (float*)w;    w += (size_t)Ne * 4;
    ushort_t* W1p  = (ushort_t*)w; w += (size_t)256 * KAP * 2;
    ushort_t* Wbp  = (ushort_t*)w; w += (size_t)256 * 256 * 2;
    ushort_t* Wtp  = (ushort_t*)w; w += (size_t)256 * 256 * 2;

    float* out = (float*)d_out;
    dim3 b256(256);
    dim3 gN((Nn + 255) / 256), gE((Ne + 255) / 256);
    dim3 gAgg((Nn + 3) / 4);
    dim3 gGemmN((Nn + 63) / 64);
    const int ntiles = (Ne + 63) / 64;
    dim3 gMlp(1024);
    const int n4 = Nn * HDIM / 4;
    dim3 gCvt((n4 + 255) / 256);

    // ---- weight prep (bf16) ----
    prep_w_kernel<<<dim3((256 * KAP + 255) / 256), b256, 0, stream>>>(W1, W1p, KA, KAP);
    prep_w_kernel<<<dim3((256 * 256 + 255) / 256), b256, 0, stream>>>(Wb, Wbp, 256, 256);
    prep_w_kernel<<<dim3((256 * 256 + 255) / 256), b256, 0, stream>>>(Wt, Wtp, 256, 256);
    f32_to_bf16_kernel<<<gCvt, b256, 0, stream>>>(x, xb, n4);

    // ---- stage A: BOLD GCN ----
    init_deg_kernel<<<gN, b256, 0, stream>>>(dinv, Nn);
    hist_deg_kernel<<<gE, b256, 0, stream>>>(dst_b, eab, dinv, Ne);
    rsqrt_kernel<<<gN, b256, 0, stream>>>(dinv, Nn);
    hipMemsetAsync(cnt, 0, (size_t)Nn * 4, stream);
    hist_cnt_kernel<<<gE, b256, 0, stream>>>(dst_b, cnt, Ne);
    scan_kernel<<<dim3(1), dim3(1024), 0, stream>>>(cnt, rptr, cur, Nn);
    fill_kernel<<<gE, b256, 0, stream>>>(src_b, dst_b, eab, dinv, cur, ssrc, snrm, Ne);
    agg_kernel<<<gAgg, b256, 0, stream>>>(xb, rptr, ssrc, snrm, dinv, aggb, Nn);
    gemm_node_kernel<0><<<gGemmN, b256, 0, stream>>>(
        aggb, Wbp, bb, x, nullptr, gs, bs, nullptr, nullptr, x1, x1b, Nn);

    // ---- temporal edge-weight MLP (persistent, dbuf) ----
    mlp_mfma_kernel<<<gMlp, b256, 0, stream>>>(
        eat, W1p, b1, g1, be1, W2, b2, wtmp, Ne, ntiles);

    // ---- stage B: temporal GCN + final LN ----
    init_deg_kernel<<<gN, b256, 0, stream>>>(dinv, Nn);
    hist_deg_kernel<<<gE, b256, 0, stream>>>(dst_t, wtmp, dinv, Ne);
    rsqrt_kernel<<<gN, b256, 0, stream>>>(dinv, Nn);
    hipMemsetAsync(cnt, 0, (size_t)Nn * 4, stream);
    hist_cnt_kernel<<<gE, b256, 0, stream>>>(dst_t, cnt, Ne);
    scan_kernel<<<dim3(1), dim3(1024), 0, stream>>>(cnt, rptr, cur, Nn);
    fill_kernel<<<gE, b256, 0, stream>>>(src_t, dst_t, wtmp, dinv, cur, ssrc, snrm, Ne);
    agg_kernel<<<gAgg, b256, 0, stream>>>(x1b, rptr, ssrc, snrm, dinv, aggb, Nn);
    gemm_node_kernel<1><<<gGemmN, b256, 0, stream>>>(
        aggb, Wtp, bt, x1, x, gt, btn, gs, bs, out, nullptr, Nn);
}

// Round 5
// 945.958 us; speedup vs baseline: 2.8206x; 1.0634x over previous
//
#include <hip/hip_runtime.h>

#define HDIM 256
#define KA 107
#define KAP 128

typedef short bf16x8 __attribute__((ext_vector_type(8)));
typedef float f32x4 __attribute__((ext_vector_type(4)));
typedef unsigned short ushort_t;

__device__ inline unsigned short f2bf(float f) {
    union { float f; unsigned u; } v; v.f = f;
    unsigned r = v.u + 0x7fff + ((v.u >> 16) & 1);
    return (unsigned short)(r >> 16);
}

__device__ inline unsigned cvt_pk_bf16(float a, float b) {
    unsigned r;
    asm("v_cvt_pk_bf16_f32 %0, %1, %2" : "=v"(r) : "v"(a), "v"(b));
    return r;   // low16 = bf16(a), high16 = bf16(b)
}

__device__ inline float bf_lo(unsigned u) { union { unsigned v; float f; } x; x.v = u << 16; return x.f; }
__device__ inline float bf_hi(unsigned u) { union { unsigned v; float f; } x; x.v = u & 0xffff0000u; return x.f; }

__device__ inline float4 guarded_load4(const float* p, size_t off, size_t tot) {
    if (off + 4 <= tot) return *(const float4*)(p + off);
    float4 r = {0.f, 0.f, 0.f, 0.f};
    float* rr = (float*)&r;
    for (int e = 0; e < 4; ++e) if (off + e < tot) rr[e] = p[off + e];
    return r;
}

// ---------------- small kernels ----------------

__global__ void init_deg_kernel(float* deg, int n) {
    int i = blockIdx.x * 256 + threadIdx.x;
    if (i < n) deg[i] = 1.0f;   // self-loop weight
}

// fused: weighted degree + count histogram in one pass over dst
__global__ void hist_kernel(const int* __restrict__ dst, const float* __restrict__ w,
                            float* deg, int* cnt, int ne) {
    int e = blockIdx.x * 256 + threadIdx.x;
    if (e < ne) {
        int d = dst[e];
        atomicAdd(&deg[d], w[e]);
        atomicAdd(&cnt[d], 1);
    }
}

__global__ void rsqrt_kernel(float* deg, int n) {
    int i = blockIdx.x * 256 + threadIdx.x;
    if (i < n) { float d = deg[i]; deg[i] = d > 0.f ? rsqrtf(d) : 0.f; }
}

// f32 -> bf16 mirror (float4 -> uint2)
__global__ void f32_to_bf16_kernel(const float* __restrict__ in, ushort_t* __restrict__ out, int n4) {
    int i = blockIdx.x * 256 + threadIdx.x;
    if (i < n4) {
        float4 v = ((const float4*)in)[i];
        uint2 o;
        o.x = cvt_pk_bf16(v.x, v.y);
        o.y = cvt_pk_bf16(v.z, v.w);
        ((uint2*)out)[i] = o;
    }
}

// single-block exclusive scan over cnt[n] -> rptr[0..n], cur[i]=rptr[i]
__global__ __launch_bounds__(1024) void scan_kernel(const int* __restrict__ cnt,
                                                    int* __restrict__ rptr,
                                                    int* __restrict__ cur, int n) {
    const int per = (n + 1023) / 1024;
    const int tid = threadIdx.x;
    const int start = tid * per;
    const int end = min(start + per, n);
    int local = 0;
    for (int i = start; i < end; ++i) local += cnt[i];
    const int lane = tid & 63, wid = tid >> 6;
    int incl = local;
    for (int d = 1; d < 64; d <<= 1) { int m = __shfl_up(incl, d); if (lane >= d) incl += m; }
    __shared__ int wsum[16];
    if (lane == 63) wsum[wid] = incl;
    __syncthreads();
    if (tid < 16) {
        int v = wsum[tid];
        int iv = v;
        for (int d = 1; d < 16; d <<= 1) { int m = __shfl_up(iv, d, 16); if (tid >= d) iv += m; }
        wsum[tid] = iv - v;
    }
    __syncthreads();
    int run = (incl - local) + wsum[wid];
    for (int i = start; i < end; ++i) { int cc = cnt[i]; rptr[i] = run; cur[i] = run; run += cc; }
    if (start < n && end == n) rptr[n] = run;
}

__global__ void fill_kernel(const int* __restrict__ src, const int* __restrict__ dst,
                            const float* __restrict__ w, const float* __restrict__ dinv,
                            int* cur, int* __restrict__ ssrc, float* __restrict__ snrm, int ne) {
    int e = blockIdx.x * 256 + threadIdx.x;
    if (e < ne) {
        int s = src[e], d = dst[e];
        int pos = atomicAdd(&cur[d], 1);
        ssrc[pos] = s;
        snrm[pos] = dinv[s] * w[e] * dinv[d];
    }
}

// one wave per dst node; 4 independent edge chains (4 gathers in flight)
__global__ __launch_bounds__(256) void agg_kernel(const ushort_t* __restrict__ Xb,
                                                  const int* __restrict__ rptr,
                                                  const int* __restrict__ ssrc,
                                                  const float* __restrict__ snrm,
                                                  const float* __restrict__ dinv,
                                                  ushort_t* __restrict__ out, int n) {
    const int v = blockIdx.x * 4 + (threadIdx.x >> 6);
    if (v >= n) return;
    const int lane = threadIdx.x & 63;
    const float dv = dinv[v];
    const uint2 xv = *(const uint2*)(Xb + (size_t)v * HDIM + lane * 4);
    const float dv2 = dv * dv;
    float a[4][4];
#pragma unroll
    for (int c = 0; c < 4; ++c)
#pragma unroll
        for (int k = 0; k < 4; ++k) a[c][k] = 0.f;
    a[0][0] = dv2 * bf_lo(xv.x); a[0][1] = dv2 * bf_hi(xv.x);
    a[0][2] = dv2 * bf_lo(xv.y); a[0][3] = dv2 * bf_hi(xv.y);

    const int b = rptr[v];
    const int total = rptr[v + 1] - b;
    uint2 pv[4]; float pn[4];
#pragma unroll
    for (int c = 0; c < 4; ++c) {
        if (c < total) {
            int s = ssrc[b + c]; pn[c] = snrm[b + c];
            pv[c] = *(const uint2*)(Xb + (size_t)s * HDIM + lane * 4);
        }
    }
    for (int base = 0; base < total; base += 4) {
#pragma unroll
        for (int c = 0; c < 4; ++c) {
            if (base + c < total) {
                uint2 cv = pv[c]; float cn = pn[c];
                int nx = base + 4 + c;
                if (nx < total) {
                    int s = ssrc[b + nx]; pn[c] = snrm[b + nx];
                    pv[c] = *(const uint2*)(Xb + (size_t)s * HDIM + lane * 4);
                }
                a[c][0] = fmaf(cn, bf_lo(cv.x), a[c][0]);
                a[c][1] = fmaf(cn, bf_hi(cv.x), a[c][1]);
                a[c][2] = fmaf(cn, bf_lo(cv.y), a[c][2]);
                a[c][3] = fmaf(cn, bf_hi(cv.y), a[c][3]);
            }
        }
    }
    float r0 = (a[0][0] + a[1][0]) + (a[2][0] + a[3][0]);
    float r1 = (a[0][1] + a[1][1]) + (a[2][1] + a[3][1]);
    float r2 = (a[0][2] + a[1][2]) + (a[2][2] + a[3][2]);
    float r3 = (a[0][3] + a[1][3]) + (a[2][3] + a[3][3]);
    uint2 o;
    o.x = cvt_pk_bf16(r0, r1);
    o.y = cvt_pk_bf16(r2, r3);
    *(uint2*)(out + (size_t)v * HDIM + lane * 4) = o;
}

// ---------------- bf16 weight prep (generic, K -> KP padded) ----------------
__global__ void prep_w_kernel(const float* __restrict__ W, ushort_t* __restrict__ Wp,
                              int K, int KP) {
    int i = blockIdx.x * 256 + threadIdx.x;
    if (i < 256 * KP) {
        int n = i / KP, k = i - n * KP;
        Wp[i] = (k < K) ? f2bf(W[n * K + k]) : (ushort_t)0;
    }
}

// ---------------- edge MLP: persistent, dbuf LDS, row-wise staging, W in regs ----------------
// Lane (g=l>>4, c=l&15) holds rows m = rt*16+c, cols n = wv*64 + nt*16 + g*4 + reg.
__global__ __launch_bounds__(256) void mlp_mfma_kernel(
    const float* __restrict__ A,            // [M][107] f32
    const ushort_t* __restrict__ Wp,        // [256][128] bf16, zero-padded k>=107
    const float* __restrict__ b1v, const float* __restrict__ g1v,
    const float* __restrict__ be1v, const float* __restrict__ W2,
    const float* __restrict__ b2s, float* __restrict__ out,
    int M, int ntiles) {
    __shared__ ushort_t As[2][64][136];
    __shared__ float ps1[64][4], ps2[64][4], pd[64][4];
    const int tid = threadIdx.x;
    const int l = tid & 63, wv = tid >> 6, g = l >> 4, c = l & 15;
    const float b2sc = b2s[0];
    const size_t totElems = (size_t)M * KA;

    // one-time zero of k in [112,128) for BOTH buffers (staging never writes there;
    // k in [107,112) gets finite garbage each tile, killed by W zero-pad)
    for (int z = tid; z < 2 * 64 * 16; z += 256) {
        int buf = z >> 10;
        int rem = z & 1023;
        As[buf][rem >> 4][112 + (rem & 15)] = 0;
    }

    // hoist all W fragments (loop-invariant): wreg[ks][nt]
    bf16x8 wreg[4][4];
    {
        const ushort_t* wb = Wp + (size_t)(wv * 64 + c) * KAP + g * 8;
#pragma unroll
        for (int ks = 0; ks < 4; ++ks)
#pragma unroll
            for (int nt = 0; nt < 4; ++nt)
                wreg[ks][nt] = *(const bf16x8*)(wb + nt * 16 * KAP + ks * 32);
    }

    // staging role: 4 threads per row; thread (r=tid>>2, j=tid&3) covers k = j*4 + i*16, i<7
    const int srow = tid >> 2, sj = tid & 3;
    float4 sreg[7];

    // ---- prologue: stage tile t0 into buf 0 ----
    const int t0 = blockIdx.x;
    if (t0 < ntiles) {
        const size_t roff = (size_t)(t0 * 64 + srow) * KA + sj * 4;
#pragma unroll
        for (int i = 0; i < 7; ++i) sreg[i] = guarded_load4(A, roff + i * 16, totElems);
#pragma unroll
        for (int i = 0; i < 7; ++i) {
            uint2 o;
            o.x = cvt_pk_bf16(sreg[i].x, sreg[i].y);
            o.y = cvt_pk_bf16(sreg[i].z, sreg[i].w);
            *(uint2*)&As[0][srow][sj * 4 + i * 16] = o;
        }
    }
    __syncthreads();

    int cur = 0;
    for (int t = t0; t < ntiles; t += gridDim.x) {
        const int tn = t + gridDim.x;
        const bool have_next = tn < ntiles;
        // (A) issue next tile's loads early
        if (have_next) {
            const size_t roff = (size_t)(tn * 64 + srow) * KA + sj * 4;
#pragma unroll
            for (int i = 0; i < 7; ++i) sreg[i] = guarded_load4(A, roff + i * 16, totElems);
        }

        // (B) MFMA on As[cur]
        f32x4 acc[4][4];
#pragma unroll
        for (int rt = 0; rt < 4; ++rt)
#pragma unroll
            for (int nt = 0; nt < 4; ++nt) acc[rt][nt] = (f32x4){0.f, 0.f, 0.f, 0.f};
        __builtin_amdgcn_s_setprio(1);
#pragma unroll
        for (int ks = 0; ks < 4; ++ks) {
            bf16x8 af[4];
#pragma unroll
            for (int rt = 0; rt < 4; ++rt)
                af[rt] = *(const bf16x8*)&As[cur][rt * 16 + c][ks * 32 + g * 8];
#pragma unroll
            for (int nt = 0; nt < 4; ++nt)
#pragma unroll
                for (int rt = 0; rt < 4; ++rt)
                    acc[rt][nt] = __builtin_amdgcn_mfma_f32_16x16x32_bf16(wreg[ks][nt], af[rt], acc[rt][nt], 0, 0, 0);
        }
        __builtin_amdgcn_s_setprio(0);

        const int nb = wv * 64 + (g << 2);
        const int m0 = t * 64;
        // (C) pass 1: bias + row sums
#pragma unroll
        for (int rt = 0; rt < 4; ++rt) {
            float s1 = 0.f, s2 = 0.f;
#pragma unroll
            for (int nt = 0; nt < 4; ++nt) {
                const float4 b4 = *(const float4*)(b1v + nb + nt * 16);
                f32x4 v = acc[rt][nt];
                v[0] += b4.x; v[1] += b4.y; v[2] += b4.z; v[3] += b4.w;
                acc[rt][nt] = v;
                s1 += v[0] + v[1] + v[2] + v[3];
                s2 += v[0] * v[0] + v[1] * v[1] + v[2] * v[2] + v[3] * v[3];
            }
            s1 += __shfl_xor(s1, 16); s1 += __shfl_xor(s1, 32);
            s2 += __shfl_xor(s2, 16); s2 += __shfl_xor(s2, 32);
            if (l < 16) { ps1[rt * 16 + c][wv] = s1; ps2[rt * 16 + c][wv] = s2; }
        }
        __syncthreads();   // barrier 1: ps published
        // (D) pass 2: LN + relu + dot(W2) -> pd
#pragma unroll
        for (int rt = 0; rt < 4; ++rt) {
            float4 p1 = *(const float4*)ps1[rt * 16 + c];
            float4 p2 = *(const float4*)ps2[rt * 16 + c];
            float s1 = p1.x + p1.y + p1.z + p1.w;
            float s2 = p2.x + p2.y + p2.z + p2.w;
            float mu = s1 * (1.f / HDIM);
            float var = s2 * (1.f / HDIM) - mu * mu;
            float rs = rsqrtf(var + 1e-5f);
            float dacc = 0.f;
#pragma unroll
            for (int nt = 0; nt < 4; ++nt) {
                const float4 g4 = *(const float4*)(g1v + nb + nt * 16);
                const float4 e4 = *(const float4*)(be1v + nb + nt * 16);
                const float4 w4 = *(const float4*)(W2 + nb + nt * 16);
                f32x4 v = acc[rt][nt];
                float y0 = fmaxf((v[0] - mu) * rs * g4.x + e4.x, 0.f);
                float y1 = fmaxf((v[1] - mu) * rs * g4.y + e4.y, 0.f);
                float y2 = fmaxf((v[2] - mu) * rs * g4.z + e4.z, 0.f);
                float y3 = fmaxf((v[3] - mu) * rs * g4.w + e4.w, 0.f);
                dacc = fmaf(y0, w4.x, dacc); dacc = fmaf(y1, w4.y, dacc);
                dacc = fmaf(y2, w4.z, dacc); dacc = fmaf(y3, w4.w, dacc);
            }
            dacc += __shfl_xor(dacc, 16); dacc += __shfl_xor(dacc, 32);
            if (l < 16) pd[rt * 16 + c][wv] = dacc;
        }
        // (E) write next buffer (no reader of As[cur^1] until after barrier 2)
        if (have_next) {
#pragma unroll
            for (int i = 0; i < 7; ++i) {
                uint2 o;
                o.x = cvt_pk_bf16(sreg[i].x, sreg[i].y);
                o.y = cvt_pk_bf16(sreg[i].z, sreg[i].w);
                *(uint2*)&As[cur ^ 1][srow][sj * 4 + i * 16] = o;
            }
        }
        __syncthreads();   // barrier 2: pd published + As[cur^1] complete
        // (F) out store for tile t
        if (tid < 64) {
            float4 p = *(const float4*)pd[tid];
            int gr = m0 + tid;
            if (gr < M) out[gr] = p.x + p.y + p.z + p.w + b2sc;
        }
        cur ^= 1;
    }
}

// ---------------- node GEMM: bf16 MFMA, C^T epilogue, fused LN(s) ----------------
// MODE 0: out = relu(LN(A@W^T + bias + res; g1,b1)); also writes bf16 mirror out_bf
// MODE 1: y = relu(LN(A@W^T + bias + res; g1,b1)); out = LN(y + orig; g2,b2)
template <int MODE>
__global__ __launch_bounds__(256) void gemm_node_kernel(
    const ushort_t* __restrict__ A,   // [M][256] bf16
    const ushort_t* __restrict__ Wp,  // [256][256] bf16
    const float* __restrict__ bias, const float* __restrict__ res,
    const float* __restrict__ orig,
    const float* __restrict__ g1v, const float* __restrict__ b1v,
    const float* __restrict__ g2v, const float* __restrict__ b2v,
    float* __restrict__ out, ushort_t* __restrict__ out_bf, int M) {
    __shared__ ushort_t As[64][264];
    __shared__ float ps1[64][4], ps2[64][4], ps3[64][4], ps4[64][4];
    const int tid = threadIdx.x;
    const int m0 = blockIdx.x * 64;
    const int l = tid & 63, wv = tid >> 6, g = l >> 4, c = l & 15;

    {
        const int r = tid >> 2, j = tid & 3;
        const ushort_t* gsrc = A + (size_t)(m0 + r) * HDIM;
        const bool ok = (m0 + r) < M;
#pragma unroll
        for (int i = 0; i < 8; ++i) {
            const int ci = i * 4 + j;
            bf16x8 v = (bf16x8){0,0,0,0,0,0,0,0};
            if (ok) v = *(const bf16x8*)(gsrc + ci * 8);
            *(bf16x8*)&As[r][ci * 8] = v;
        }
    }
    __syncthreads();

    f32x4 acc[4][4];
#pragma unroll
    for (int rt = 0; rt < 4; ++rt)
#pragma unroll
        for (int nt = 0; nt < 4; ++nt) acc[rt][nt] = (f32x4){0.f, 0.f, 0.f, 0.f};

    const ushort_t* wb = Wp + (size_t)(wv * 64 + c) * HDIM + g * 8;
    __builtin_amdgcn_s_setprio(1);
#pragma unroll
    for (int ks = 0; ks < 8; ++ks) {
        bf16x8 af[4];
#pragma unroll
        for (int rt = 0; rt < 4; ++rt)
            af[rt] = *(const bf16x8*)&As[rt * 16 + c][ks * 32 + g * 8];
#pragma unroll
        for (int nt = 0; nt < 4; ++nt) {
            bf16x8 bfr = *(const bf16x8*)(wb + nt * 16 * HDIM + ks * 32);
#pragma unroll
            for (int rt = 0; rt < 4; ++rt)
                acc[rt][nt] = __builtin_amdgcn_mfma_f32_16x16x32_bf16(bfr, af[rt], acc[rt][nt], 0, 0, 0);
        }
    }
    __builtin_amdgcn_s_setprio(0);

    const int nb = wv * 64 + (g << 2);
#pragma unroll
    for (int rt = 0; rt < 4; ++rt) {
        const int m = m0 + rt * 16 + c;
        const bool vm = m < M;
        const float* rrow = res + (size_t)m * HDIM + nb;
        float s1 = 0.f, s2 = 0.f;
#pragma unroll
        for (int nt = 0; nt < 4; ++nt) {
            const float4 b4 = *(const float4*)(bias + nb + nt * 16);
            float4 r4 = {0.f, 0.f, 0.f, 0.f};
            if (vm) r4 = *(const float4*)(rrow + nt * 16);
            f32x4 v = acc[rt][nt];
            v[0] += b4.x + r4.x; v[1] += b4.y + r4.y;
            v[2] += b4.z + r4.z; v[3] += b4.w + r4.w;
            acc[rt][nt] = v;
            s1 += v[0] + v[1] + v[2] + v[3];
            s2 += v[0] * v[0] + v[1] * v[1] + v[2] * v[2] + v[3] * v[3];
        }
        s1 += __shfl_xor(s1, 16); s1 += __shfl_xor(s1, 32);
        s2 += __shfl_xor(s2, 16); s2 += __shfl_xor(s2, 32);
        if (l < 16) { ps1[rt * 16 + c][wv] = s1; ps2[rt * 16 + c][wv] = s2; }
    }
    __syncthreads();
#pragma unroll
    for (int rt = 0; rt < 4; ++rt) {
        const int m = m0 + rt * 16 + c;
        const bool vm = m < M;
        float4 p1 = *(const float4*)ps1[rt * 16 + c];
        float4 p2 = *(const float4*)ps2[rt * 16 + c];
        float s1 = p1.x + p1.y + p1.z + p1.w;
        float s2 = p2.x + p2.y + p2.z + p2.w;
        float mu = s1 * (1.f / HDIM);
        float var = s2 * (1.f / HDIM) - mu * mu;
        float rs = rsqrtf(var + 1e-5f);
        if constexpr (MODE == 0) {
            float* orow = out + (size_t)m * HDIM + nb;
            ushort_t* obrow = out_bf + (size_t)m * HDIM + nb;
#pragma unroll
            for (int nt = 0; nt < 4; ++nt) {
                const float4 g4 = *(const float4*)(g1v + nb + nt * 16);
                const float4 e4 = *(const float4*)(b1v + nb + nt * 16);
                f32x4 v = acc[rt][nt];
                float4 o;
                o.x = fmaxf((v[0] - mu) * rs * g4.x + e4.x, 0.f);
                o.y = fmaxf((v[1] - mu) * rs * g4.y + e4.y, 0.f);
                o.z = fmaxf((v[2] - mu) * rs * g4.z + e4.z, 0.f);
                o.w = fmaxf((v[3] - mu) * rs * g4.w + e4.w, 0.f);
                if (vm) {
                    *(float4*)(orow + nt * 16) = o;
                    uint2 ob;
                    ob.x = cvt_pk_bf16(o.x, o.y);
                    ob.y = cvt_pk_bf16(o.z, o.w);
                    *(uint2*)(obrow + nt * 16) = ob;
                }
            }
        } else {
            const float* grow = orig + (size_t)m * HDIM + nb;
            float t1 = 0.f, t2 = 0.f;
#pragma unroll
            for (int nt = 0; nt < 4; ++nt) {
                const float4 g4 = *(const float4*)(g1v + nb + nt * 16);
                const float4 e4 = *(const float4*)(b1v + nb + nt * 16);
                float4 o4 = {0.f, 0.f, 0.f, 0.f};
                if (vm) o4 = *(const float4*)(grow + nt * 16);
                f32x4 v = acc[rt][nt];
                f32x4 u;
                u[0] = fmaxf((v[0] - mu) * rs * g4.x + e4.x, 0.f) + o4.x;
                u[1] = fmaxf((v[1] - mu) * rs * g4.y + e4.y, 0.f) + o4.y;
                u[2] = fmaxf((v[2] - mu) * rs * g4.z + e4.z, 0.f) + o4.z;
                u[3] = fmaxf((v[3] - mu) * rs * g4.w + e4.w, 0.f) + o4.w;
                acc[rt][nt] = u;
                t1 += u[0] + u[1] + u[2] + u[3];
                t2 += u[0] * u[0] + u[1] * u[1] + u[2] * u[2] + u[3] * u[3];
            }
            t1 += __shfl_xor(t1, 16); t1 += __shfl_xor(t1, 32);
            t2 += __shfl_xor(t2, 16); t2 += __shfl_xor(t2, 32);
            if (l < 16) { ps3[rt * 16 + c][wv] = t1; ps4[rt * 16 + c][wv] = t2; }
        }
    }
    if constexpr (MODE == 1) {
        __syncthreads();
#pragma unroll
        for (int rt = 0; rt < 4; ++rt) {
            const int m = m0 + rt * 16 + c;
            const bool vm = m < M;
            float4 p1 = *(const float4*)ps3[rt * 16 + c];
            float4 p2 = *(const float4*)ps4[rt * 16 + c];
            float s1 = p1.x + p1.y + p1.z + p1.w;
            float s2 = p2.x + p2.y + p2.z + p2.w;
            float mu2 = s1 * (1.f / HDIM);
            float var2 = s2 * (1.f / HDIM) - mu2 * mu2;
            float rs2 = rsqrtf(var2 + 1e-5f);
            float* orow = out + (size_t)m * HDIM + nb;
#pragma unroll
            for (int nt = 0; nt < 4; ++nt) {
                const float4 g4 = *(const float4*)(g2v + nb + nt * 16);
                const float4 e4 = *(const float4*)(b2v + nb + nt * 16);
                f32x4 u = acc[rt][nt];
                float4 o;
                o.x = (u[0] - mu2) * rs2 * g4.x + e4.x;
                o.y = (u[1] - mu2) * rs2 * g4.y + e4.y;
                o.z = (u[2] - mu2) * rs2 * g4.z + e4.z;
                o.w = (u[3] - mu2) * rs2 * g4.w + e4.w;
                if (vm) *(float4*)(orow + nt * 16) = o;
            }
        }
    }
}

// ---------------- launch ----------------

extern "C" void kernel_launch(void* const* d_in, const int* in_sizes, int n_in,
                              void* d_out, int out_size, void* d_ws, size_t ws_size,
                              hipStream_t stream) {
    const float* x    = (const float*)d_in[0];
    const int*   eib  = (const int*)d_in[1];
    const float* eab  = (const float*)d_in[2];
    const int*   eit  = (const int*)d_in[3];
    const float* eat  = (const float*)d_in[4];
    const float* Wb   = (const float*)d_in[5];
    const float* bb   = (const float*)d_in[6];
    const float* Wt   = (const float*)d_in[7];
    const float* bt   = (const float*)d_in[8];
    const float* W1   = (const float*)d_in[9];
    const float* b1   = (const float*)d_in[10];
    const float* g1   = (const float*)d_in[11];
    const float* be1  = (const float*)d_in[12];
    const float* W2   = (const float*)d_in[13];
    const float* b2   = (const float*)d_in[14];
    const float* gs   = (const float*)d_in[15];
    const float* bs   = (const float*)d_in[16];
    const float* gt   = (const float*)d_in[17];
    const float* btn  = (const float*)d_in[18];

    const int Nn = in_sizes[0] / HDIM;     // 50000
    const int Ne = in_sizes[2];            // 800000

    const int* src_b = eib;  const int* dst_b = eib + Ne;
    const int* src_t = eit;  const int* dst_t = eit + Ne;

    char* w = (char*)d_ws;
    float*    x1   = (float*)w;    w += (size_t)Nn * HDIM * 4;
    ushort_t* aggb = (ushort_t*)w; w += (size_t)Nn * HDIM * 2;
    ushort_t* xb   = (ushort_t*)w; w += (size_t)Nn * HDIM * 2;
    ushort_t* x1b  = (ushort_t*)w; w += (size_t)Nn * HDIM * 2;
    float*    wtmp = (float*)w;    w += (size_t)Ne * 4;
    float*    dinv = (float*)w;    w += (size_t)Nn * 4;
    int*      cnt  = (int*)w;      w += (size_t)Nn * 4;
    int*      rptr = (int*)w;      w += (size_t)(Nn + 4) * 4;
    int*      cur  = (int*)w;      w += (size_t)Nn * 4;
    int*      ssrc = (int*)w;      w += (size_t)Ne * 4;
    float*    snrm = (float*)w;    w += (size_t)Ne * 4;
    ushort_t* W1p  = (ushort_t*)w; w += (size_t)256 * KAP * 2;
    ushort_t* Wbp  = (ushort_t*)w; w += (size_t)256 * 256 * 2;
    ushort_t* Wtp  = (ushort_t*)w; w += (size_t)256 * 256 * 2;

    float* out = (float*)d_out;
    dim3 b256(256);
    dim3 gN((Nn + 255) / 256), gE((Ne + 255) / 256);
    dim3 gAgg((Nn + 3) / 4);
    dim3 gGemmN((Nn + 63) / 64);
    const int ntiles = (Ne + 63) / 64;
    dim3 gMlp(512);
    const int n4 = Nn * HDIM / 4;
    dim3 gCvt((n4 + 255) / 256);

    // ---- weight prep (bf16) ----
    prep_w_kernel<<<dim3((256 * KAP + 255) / 256), b256, 0, stream>>>(W1, W1p, KA, KAP);
    prep_w_kernel<<<dim3((256 * 256 + 255) / 256), b256, 0, stream>>>(Wb, Wbp, 256, 256);
    prep_w_kernel<<<dim3((256 * 256 + 255) / 256), b256, 0, stream>>>(Wt, Wtp, 256, 256);
    f32_to_bf16_kernel<<<gCvt, b256, 0, stream>>>(x, xb, n4);

    // ---- stage A: BOLD GCN ----
    init_deg_kernel<<<gN, b256, 0, stream>>>(dinv, Nn);
    hipMemsetAsync(cnt, 0, (size_t)Nn * 4, stream);
    hist_kernel<<<gE, b256, 0, stream>>>(dst_b, eab, dinv, cnt, Ne);
    rsqrt_kernel<<<gN, b256, 0, stream>>>(dinv, Nn);
    scan_kernel<<<dim3(1), dim3(1024), 0, stream>>>(cnt, rptr, cur, Nn);
    fill_kernel<<<gE, b256, 0, stream>>>(src_b, dst_b, eab, dinv, cur, ssrc, snrm, Ne);
    agg_kernel<<<gAgg, b256, 0, stream>>>(xb, rptr, ssrc, snrm, dinv, aggb, Nn);
    gemm_node_kernel<0><<<gGemmN, b256, 0, stream>>>(
        aggb, Wbp, bb, x, nullptr, gs, bs, nullptr, nullptr, x1, x1b, Nn);

    // ---- temporal edge-weight MLP (persistent, dbuf, W-in-regs) ----
    mlp_mfma_kernel<<<gMlp, b256, 0, stream>>>(
        eat, W1p, b1, g1, be1, W2, b2, wtmp, Ne, ntiles);

    // ---- stage B: temporal GCN + final LN ----
    init_deg_kernel<<<gN, b256, 0, stream>>>(dinv, Nn);
    hipMemsetAsync(cnt, 0, (size_t)Nn * 4, stream);
    hist_kernel<<<gE, b256, 0, stream>>>(dst_t, wtmp, dinv, cnt, Ne);
    rsqrt_kernel<<<gN, b256, 0, stream>>>(dinv, Nn);
    scan_kernel<<<dim3(1), dim3(1024), 0, stream>>>(cnt, rptr, cur, Nn);
    fill_kernel<<<gE, b256, 0, stream>>>(src_t, dst_t, wtmp, dinv, cur, ssrc, snrm, Ne);
    agg_kernel<<<gAgg, b256, 0, stream>>>(x1b, rptr, ssrc, snrm, dinv, aggb, Nn);
    gemm_node_kernel<1><<<gGemmN, b256, 0, stream>>>(
        aggb, Wtp, bt, x1, x, gt, btn, gs, bs, out, nullptr, Nn);
}